// Round 2
// baseline (624.573 us; speedup 1.0000x reference)
//
#include <hip/hip_runtime.h>
#include <hip/hip_bf16.h>
#include <stdint.h>

typedef __bf16 bf16_t;
typedef bf16_t bf16x8 __attribute__((ext_vector_type(8)));
typedef bf16_t bf16x4 __attribute__((ext_vector_type(4)));
typedef float f32x4 __attribute__((ext_vector_type(4)));

#define B_ 2
#define Q_ 1024
#define PAST_ 1024
#define T_ 2048
#define HID_ 4096
#define NH_ 32
#define NKV_ 8
#define HD_ 128
#define SCALE_ 0.08838834764831845f

__device__ __forceinline__ void async_cp16(const bf16_t* g, bf16_t* l) {
  __builtin_amdgcn_global_load_lds((__attribute__((address_space(1))) void*)g,
                                   (__attribute__((address_space(3))) void*)l, 16, 0, 0);
}

// ---------------- fp32 -> bf16 convert (8 elems/thread) ----------------
__global__ void cvt_f32_bf16(const float* __restrict__ src, bf16_t* __restrict__ dst, size_t n) {
  size_t i = ((size_t)blockIdx.x * blockDim.x + threadIdx.x) * 8;
  if (i >= n) return;
  float4 a = *(const float4*)(src + i);
  float4 b = *(const float4*)(src + i + 4);
  bf16x8 o;
  o[0] = (bf16_t)a.x; o[1] = (bf16_t)a.y; o[2] = (bf16_t)a.z; o[3] = (bf16_t)a.w;
  o[4] = (bf16_t)b.x; o[5] = (bf16_t)b.y; o[6] = (bf16_t)b.z; o[7] = (bf16_t)b.w;
  *(bf16x8*)(dst + i) = o;
}

// ---------------- past KV copy: fp32 -> d_out, bf16 K -> cache ----------------
__global__ void copy_past(const float* __restrict__ pk, const float* __restrict__ pv,
                          float* __restrict__ oK, float* __restrict__ oV,
                          bf16_t* __restrict__ Kall) {
  size_t i = ((size_t)blockIdx.x * 256 + threadIdx.x) * 4;
  if (i >= (size_t)B_ * NKV_ * PAST_ * HD_) return;
  int d = (int)(i & 127);
  size_t r = i >> 7;
  int t = (int)(r & 1023); r >>= 10;
  int g = (int)(r & 7); int b = (int)(r >> 3);
  size_t dst = (((size_t)b * NKV_ + g) * T_ + t) * HD_ + d;
  float4 k4 = *(const float4*)(pk + i);
  float4 v4 = *(const float4*)(pv + i);
  *(float4*)(oK + dst) = k4;
  *(float4*)(oV + dst) = v4;
  bf16x4 kb; kb[0] = (bf16_t)k4.x; kb[1] = (bf16_t)k4.y; kb[2] = (bf16_t)k4.z; kb[3] = (bf16_t)k4.w;
  *(bf16x4*)(Kall + dst) = kb;
}

// ---------------- build transposed V cache: Vt[b][g][d][t] bf16 ----------------
__global__ void build_vt(const float* __restrict__ past_v, const float* __restrict__ QKV,
                         bf16_t* __restrict__ Vt) {
  __shared__ bf16_t tile[64][136];
  const int tid = threadIdx.x;
  const int t0 = blockIdx.x * 64, g = blockIdx.y, b = blockIdx.z;
#pragma unroll
  for (int k = 0; k < 8; ++k) {
    int idx = k * 256 + tid;
    int t = idx >> 5, dc = (idx & 31) * 4;
    int tt = t0 + t;
    const float* src = (tt < PAST_)
        ? past_v + ((((size_t)b * NKV_ + g) * PAST_ + tt) * HD_ + dc)
        : QKV + (((size_t)b * Q_ + (tt - PAST_)) * 6144 + 5120 + g * HD_ + dc);
    float4 v4 = *(const float4*)src;
    tile[t][dc] = (bf16_t)v4.x; tile[t][dc + 1] = (bf16_t)v4.y;
    tile[t][dc + 2] = (bf16_t)v4.z; tile[t][dc + 3] = (bf16_t)v4.w;
  }
  __syncthreads();
#pragma unroll
  for (int k = 0; k < 4; ++k) {
    int idx = k * 256 + tid;
    int d = idx >> 3, c = idx & 7;
    bf16x8 o;
#pragma unroll
    for (int j = 0; j < 8; ++j) o[j] = tile[c * 8 + j][d];
    *(bf16x8*)(Vt + ((((size_t)b * NKV_ + g) * HD_ + d) * T_) + t0 + c * 8) = o;
  }
}

// ---------------- 256x256 8-phase GEMM: C[M,N] = A[M,K] @ W[N,K]^T ----------------
// 512 thr = 8 waves (2M x 4N), per-wave 128x64 out, BK=64, 2x dbuf LDS (128 KiB).
// Raw s_barrier + counted vmcnt(8) (never 0 in steady state) keeps prefetch loads
// in flight across barriers; setprio(1) wraps each 16-MFMA quadrant cluster.
// LDS layout: row-major [256][64] per matrix, 16B chunk c of row r holds global
// chunk c^(r&7) (pre-swizzled global src; linear gload_lds dest) -> conflict-free
// ds_read_b128 (same scheme as prior kernel, measured 0 bank conflicts).
__device__ __forceinline__ void stage_tile(const bf16_t* __restrict__ G, int ldg,
                                           bf16_t* __restrict__ L, int tid) {
#pragma unroll
  for (int t = 0; t < 4; ++t) {
    int c = t * 512 + tid;
    int row = c >> 3, sc = (c & 7) ^ (row & 7);
    int cb = t * 512 + (tid & 448);  // wave-uniform LDS chunk base
    async_cp16(G + (size_t)row * ldg + sc * 8, L + (size_t)cb * 8);
  }
}

__global__ __launch_bounds__(512, 2)
void gemm256(const bf16_t* __restrict__ A, const bf16_t* __restrict__ W,
             float* __restrict__ C, int M, int N, int K) {
  __shared__ bf16_t sm[2][2][16384];  // [buf][A|B][256*64]
  const int tid = threadIdx.x;
  const int lane = tid & 63;
  const int quad = lane >> 4, l15 = lane & 15;
  const int wave = tid >> 6;
  const int wm = wave >> 2, wn = wave & 3;
  const int bm = blockIdx.y * 256, bn = blockIdx.x * 256;
  const int NT = K >> 6;

  const bf16_t* Ag = A + (size_t)bm * K;
  const bf16_t* Wg = W + (size_t)bn * K;

  f32x4 acc[8][4] = {};

  // prologue: stage tiles 0 and 1
  stage_tile(Ag, K, &sm[0][0][0], tid);
  stage_tile(Wg, K, &sm[0][1][0], tid);
  stage_tile(Ag + 64, K, &sm[1][0][0], tid);
  stage_tile(Wg + 64, K, &sm[1][1][0], tid);
  asm volatile("s_waitcnt vmcnt(8)" ::: "memory");  // tile 0 landed; tile 1 in flight
  __builtin_amdgcn_s_barrier();

  const int arow = wm * 128 + l15;
  const int brow = wn * 64 + l15;
  const int pq = l15 & 7;

  for (int t = 0; t < NT; ++t) {
    const bf16_t* lA = &sm[t & 1][0][0];
    const bf16_t* lB = &sm[t & 1][1][0];
    const int k2 = (t + 2) << 6;
    bf16x8 af[4][2], bf01[2][2], bf23[2][2];

    // ---- P1: read A[m0-3], B[n0-1]; compute quadrant (m0-3, n0-1) ----
#pragma unroll
    for (int m = 0; m < 4; ++m)
#pragma unroll
      for (int kk = 0; kk < 2; ++kk)
        af[m][kk] = *(const bf16x8*)(lA + (arow + m * 16) * 64 + ((((kk << 2) + quad) ^ pq) << 3));
#pragma unroll
    for (int n = 0; n < 2; ++n)
#pragma unroll
      for (int kk = 0; kk < 2; ++kk)
        bf01[n][kk] = *(const bf16x8*)(lB + (brow + n * 16) * 64 + ((((kk << 2) + quad) ^ pq) << 3));
    __builtin_amdgcn_s_barrier();
    asm volatile("s_waitcnt lgkmcnt(0)" ::: "memory");
    __builtin_amdgcn_sched_barrier(0);
    __builtin_amdgcn_s_setprio(1);
#pragma unroll
    for (int m = 0; m < 4; ++m)
#pragma unroll
      for (int n = 0; n < 2; ++n)
#pragma unroll
        for (int kk = 0; kk < 2; ++kk)
          acc[m][n] = __builtin_amdgcn_mfma_f32_16x16x32_bf16(af[m][kk], bf01[n][kk], acc[m][n], 0, 0, 0);
    __builtin_amdgcn_s_setprio(0);
    __builtin_amdgcn_s_barrier();

    // ---- P2: read B[n2-3]; compute quadrant (m0-3, n2-3) ----
#pragma unroll
    for (int n = 0; n < 2; ++n)
#pragma unroll
      for (int kk = 0; kk < 2; ++kk)
        bf23[n][kk] = *(const bf16x8*)(lB + (brow + (n + 2) * 16) * 64 + ((((kk << 2) + quad) ^ pq) << 3));
    __builtin_amdgcn_s_barrier();
    asm volatile("s_waitcnt lgkmcnt(0)" ::: "memory");
    __builtin_amdgcn_sched_barrier(0);
    __builtin_amdgcn_s_setprio(1);
#pragma unroll
    for (int m = 0; m < 4; ++m)
#pragma unroll
      for (int n = 0; n < 2; ++n)
#pragma unroll
        for (int kk = 0; kk < 2; ++kk)
          acc[m][n + 2] = __builtin_amdgcn_mfma_f32_16x16x32_bf16(af[m][kk], bf23[n][kk], acc[m][n + 2], 0, 0, 0);
    __builtin_amdgcn_s_setprio(0);
    __builtin_amdgcn_s_barrier();

    // ---- P3: read A[m4-7]; stage B(t+2) (B region of this buf fully consumed);
    //          compute quadrant (m4-7, n2-3) ----
#pragma unroll
    for (int m = 0; m < 4; ++m)
#pragma unroll
      for (int kk = 0; kk < 2; ++kk)
        af[m][kk] = *(const bf16x8*)(lA + (arow + (m + 4) * 16) * 64 + ((((kk << 2) + quad) ^ pq) << 3));
    if (t + 2 < NT) stage_tile(Wg + k2, K, &sm[t & 1][1][0], tid);
    __builtin_amdgcn_s_barrier();
    asm volatile("s_waitcnt lgkmcnt(0)" ::: "memory");
    __builtin_amdgcn_sched_barrier(0);
    __builtin_amdgcn_s_setprio(1);
#pragma unroll
    for (int m = 0; m < 4; ++m)
#pragma unroll
      for (int n = 0; n < 2; ++n)
#pragma unroll
        for (int kk = 0; kk < 2; ++kk)
          acc[m + 4][n + 2] = __builtin_amdgcn_mfma_f32_16x16x32_bf16(af[m][kk], bf23[n][kk], acc[m + 4][n + 2], 0, 0, 0);
    __builtin_amdgcn_s_setprio(0);
    __builtin_amdgcn_s_barrier();

    // ---- P4: stage A(t+2); compute quadrant (m4-7, n0-1); drain tile t+1 ----
    if (t + 2 < NT) stage_tile(Ag + k2, K, &sm[t & 1][0][0], tid);
    __builtin_amdgcn_s_barrier();
    __builtin_amdgcn_s_setprio(1);
#pragma unroll
    for (int m = 0; m < 4; ++m)
#pragma unroll
      for (int n = 0; n < 2; ++n)
#pragma unroll
        for (int kk = 0; kk < 2; ++kk)
          acc[m + 4][n] = __builtin_amdgcn_mfma_f32_16x16x32_bf16(af[m][kk], bf01[n][kk], acc[m + 4][n], 0, 0, 0);
    __builtin_amdgcn_s_setprio(0);
    if (t + 2 < NT)
      asm volatile("s_waitcnt vmcnt(8)" ::: "memory");  // tile t+1 landed; t+2 in flight
    else if (t + 2 == NT)
      asm volatile("s_waitcnt vmcnt(0)" ::: "memory");  // last prefetch: full drain
    __builtin_amdgcn_s_barrier();
  }

  // epilogue: C write
#pragma unroll
  for (int m = 0; m < 8; ++m) {
    int row0 = bm + wm * 128 + m * 16 + quad * 4;
#pragma unroll
    for (int n = 0; n < 4; ++n) {
      int col = bn + wn * 64 + n * 16 + l15;
#pragma unroll
      for (int r = 0; r < 4; ++r)
        C[(size_t)(row0 + r) * N + col] = acc[m][n][r];
    }
  }
}

// ---------------- RoPE + scatter (Q bf16 head-major; new K rows; fp32 K,V outs) ------
__global__ void rope_scatter(const float* __restrict__ QKV, const float* __restrict__ cosf,
                             const float* __restrict__ sinf, const int* __restrict__ pos_ids,
                             bf16_t* __restrict__ Qr, bf16_t* __restrict__ Kall,
                             float* __restrict__ outK, float* __restrict__ outV) {
  int m = blockIdx.x;
  int b = m >> 10, s = m & 1023;
  int pos = pos_ids[(size_t)b * Q_ + s];
  const float* row = QKV + (size_t)m * 6144;
  int tid = threadIdx.x;
  for (int p = tid; p < NH_ * 64; p += 256) {
    int h = p >> 6, d = p & 63;
    float x1 = row[h * 128 + d], x2 = row[h * 128 + d + 64];
    float c = cosf[pos * 64 + d], sn = sinf[pos * 64 + d];
    size_t qb = (((size_t)b * NH_ + h) * Q_ + s) * HD_;
    Qr[qb + d] = (bf16_t)(x1 * c - x2 * sn);
    Qr[qb + d + 64] = (bf16_t)(x2 * c + x1 * sn);
  }
  for (int p = tid; p < NKV_ * 64; p += 256) {
    int g = p >> 6, d = p & 63;
    float x1 = row[4096 + g * 128 + d], x2 = row[4096 + g * 128 + d + 64];
    float c = cosf[pos * 64 + d], sn = sinf[pos * 64 + d];
    float o1 = x1 * c - x2 * sn, o2 = x2 * c + x1 * sn;
    size_t kbi = (((size_t)b * NKV_ + g) * T_ + PAST_ + s) * HD_;
    Kall[kbi + d] = (bf16_t)o1; Kall[kbi + d + 64] = (bf16_t)o2;
    outK[kbi + d] = o1; outK[kbi + d + 64] = o2;
  }
  for (int e = tid; e < NKV_ * HD_; e += 256) {
    int g = e >> 7, d = e & 127;
    float v = row[5120 + g * 128 + d];
    outV[(((size_t)b * NKV_ + g) * T_ + PAST_ + s) * HD_ + d] = v;
  }
}

// ---------------- flash attention ----------------
__global__ __launch_bounds__(256, 4)
void attn_fwd(const bf16_t* __restrict__ Qr, const bf16_t* __restrict__ Kall,
              const bf16_t* __restrict__ Vt, bf16_t* __restrict__ Ctx) {
  __shared__ bf16_t lK[64 * 128];
  __shared__ bf16_t lV[128 * 64];
  __shared__ bf16_t lP[4 * 16 * 64];
  const int tid = threadIdx.x;
  const int wave = tid >> 6, lane = tid & 63;
  const int quad = lane >> 4, l15 = lane & 15;
  const int i = blockIdx.x;
  const int xcd = i & 7;
  const int j = i >> 3;
  const int pairsel = j & 1;
  const int idx = j >> 1;
  const int h_in = idx & 3;
  const int qt = 15 - (idx >> 2);
  const int b = pairsel, kv = xcd;
  const int h = kv * 4 + h_in;
  const int qbase = qt * 64;
  const int wq = qbase + wave * 16;
  const size_t kvbase = ((size_t)b * NKV_ + kv) * T_ * HD_;
  const size_t vtbase = ((size_t)b * NKV_ + kv) * HD_ * T_;
  bf16x8 qf[4];
  {
    const bf16_t* qg = Qr + ((((size_t)b * NH_ + h) * Q_) + wq + l15) * HD_ + quad * 8;
#pragma unroll
    for (int kk = 0; kk < 4; ++kk) qf[kk] = *(const bf16x8*)(qg + kk * 32);
  }
  f32x4 ctx[8] = {};
  float Mr[4], Lr[4];
#pragma unroll
  for (int r = 0; r < 4; ++r) { Mr[r] = -3.0e30f; Lr[r] = 0.0f; }
  bf16_t* lPw = lP + wave * 16 * 64;
  const int kend = PAST_ + qbase + 64;
  const int wlimit = PAST_ + wq + 15;
  for (int kb = 0; kb < kend; kb += 64) {
    __syncthreads();
#pragma unroll
    for (int t = 0; t < 4; ++t) {
      int cb = t * 256 + wave * 64;
      int c = cb + lane;
      int row = c >> 4, sc = (c & 15) ^ (row & 15);
      async_cp16(Kall + kvbase + (size_t)(kb + row) * HD_ + sc * 8, lK + (size_t)cb * 8);
    }
#pragma unroll
    for (int t = 0; t < 4; ++t) {
      int cb = t * 256 + wave * 64;
      int c = cb + lane;
      int d = c >> 3, sc = (c & 7) ^ (d & 7);
      async_cp16(Vt + vtbase + (size_t)d * T_ + kb + sc * 8, lV + (size_t)cb * 8);
    }
    __syncthreads();
    if (kb <= wlimit) {
      f32x4 sacc[4];
#pragma unroll
      for (int nc = 0; nc < 4; ++nc) sacc[nc] = (f32x4){0.f, 0.f, 0.f, 0.f};
#pragma unroll
      for (int nc = 0; nc < 4; ++nc)
#pragma unroll
        for (int kk = 0; kk < 4; ++kk) {
          bf16x8 bk = *(const bf16x8*)(lK + (nc * 16 + l15) * 128 + (((kk * 4 + quad) ^ l15) << 3));
          sacc[nc] = __builtin_amdgcn_mfma_f32_16x16x32_bf16(qf[kk], bk, sacc[nc], 0, 0, 0);
        }
      bool fullvis = (kb + 63 <= PAST_ + wq);
#pragma unroll
      for (int nc = 0; nc < 4; ++nc) {
        int tkey = kb + nc * 16 + l15;
#pragma unroll
        for (int r = 0; r < 4; ++r) {
          float val = sacc[nc][r] * SCALE_;
          if (!fullvis && tkey > PAST_ + wq + quad * 4 + r) val -= 10000.0f;
          sacc[nc][r] = val;
        }
      }
      float alpha[4], rs[4] = {};
#pragma unroll
      for (int r = 0; r < 4; ++r) {
        float tm = fmaxf(fmaxf(sacc[0][r], sacc[1][r]), fmaxf(sacc[2][r], sacc[3][r]));
#pragma unroll
        for (int mmk = 1; mmk < 16; mmk <<= 1) tm = fmaxf(tm, __shfl_xor(tm, mmk, 64));
        float nm = fmaxf(Mr[r], tm);
        alpha[r] = __expf(Mr[r] - nm);
        Mr[r] = nm;
      }
#pragma unroll
      for (int nc = 0; nc < 4; ++nc)
#pragma unroll
        for (int r = 0; r < 4; ++r) {
          float p = __expf(sacc[nc][r] - Mr[r]);
          rs[r] += p;
          int rho = quad * 4 + r;
          int cslot = ((nc * 2 + (l15 >> 3)) ^ (rho & 7));
          lPw[rho * 64 + cslot * 8 + (l15 & 7)] = (bf16_t)p;
        }
#pragma unroll
      for (int r = 0; r < 4; ++r) {
        float s = rs[r];
#pragma unroll
        for (int mmk = 1; mmk < 16; mmk <<= 1) s += __shfl_xor(s, mmk, 64);
        Lr[r] = Lr[r] * alpha[r] + s;
      }
#pragma unroll
      for (int nc2 = 0; nc2 < 8; ++nc2)
#pragma unroll
        for (int r = 0; r < 4; ++r) ctx[nc2][r] *= alpha[r];
      asm volatile("s_waitcnt lgkmcnt(0)" ::: "memory");
#pragma unroll
      for (int kk2 = 0; kk2 < 2; ++kk2) {
        bf16x8 ap = *(const bf16x8*)(lPw + l15 * 64 + (((kk2 * 4 + quad) ^ (l15 & 7)) << 3));
#pragma unroll
        for (int nc2 = 0; nc2 < 8; ++nc2) {
          bf16x8 bv = *(const bf16x8*)(lV + (nc2 * 16 + l15) * 64 + (((kk2 * 4 + quad) ^ (l15 & 7)) << 3));
          ctx[nc2] = __builtin_amdgcn_mfma_f32_16x16x32_bf16(ap, bv, ctx[nc2], 0, 0, 0);
        }
      }
    }
  }
  float inv[4];
#pragma unroll
  for (int r = 0; r < 4; ++r) inv[r] = 1.0f / Lr[r];
#pragma unroll
  for (int nc2 = 0; nc2 < 8; ++nc2)
#pragma unroll
    for (int r = 0; r < 4; ++r) {
      size_t row = (size_t)b * Q_ + wq + quad * 4 + r;
      Ctx[row * (NH_ * HD_) + h * HD_ + nc2 * 16 + l15] = (bf16_t)(ctx[nc2][r] * inv[r]);
    }
}

extern "C" void kernel_launch(void* const* d_in, const int* in_sizes, int n_in,
                              void* d_out, int out_size, void* d_ws, size_t ws_size,
                              hipStream_t stream) {
  const float* hidden = (const float*)d_in[0];
  const int* pos = (const int*)d_in[2];
  const float* cosf = (const float*)d_in[3];
  const float* sinf = (const float*)d_in[4];
  const float* past_k = (const float*)d_in[5];
  const float* past_v = (const float*)d_in[6];
  const float* q_w = (const float*)d_in[7];
  const float* k_w = (const float*)d_in[8];
  const float* v_w = (const float*)d_in[9];
  const float* o_w = (const float*)d_in[10];

  float* attn_out = (float*)d_out;
  float* outK = attn_out + (size_t)B_ * Q_ * HID_;
  float* outV = outK + (size_t)B_ * NKV_ * T_ * HD_;

  if (ws_size < 150994944) return;
  char* ws = (char*)d_ws;
  bf16_t* Wqkv = (bf16_t*)(ws);              // 48 MiB
  bf16_t* Xb   = (bf16_t*)(ws + 50331648);   // 16 MiB
  float*  QKV  = (float*)(ws + 67108864);    // 48 MiB
  bf16_t* Qr   = (bf16_t*)(ws + 117440512);  // 16 MiB
  bf16_t* Kall = (bf16_t*)(ws + 134217728);  // 8 MiB
  bf16_t* Vt   = (bf16_t*)(ws + 142606336);  // 8 MiB (d-major transposed V)
  bf16_t* Wo   = (bf16_t*)(ws + 67108864);   // alias QKV (converted after build_vt)
  bf16_t* Ctx  = (bf16_t*)(ws + 50331648);   // alias Xb (written after gemm1)

  cvt_f32_bf16<<<4096, 256, 0, stream>>>(hidden, Xb, 8388608);
  cvt_f32_bf16<<<8192, 256, 0, stream>>>(q_w, Wqkv, 16777216);
  cvt_f32_bf16<<<2048, 256, 0, stream>>>(k_w, Wqkv + 16777216, 4194304);
  cvt_f32_bf16<<<2048, 256, 0, stream>>>(v_w, Wqkv + 20971520, 4194304);
  copy_past<<<2048, 256, 0, stream>>>(past_k, past_v, outK, outV, Kall);
  gemm256<<<dim3(24, 8), 512, 0, stream>>>(Xb, Wqkv, QKV, 2048, 6144, 4096);
  rope_scatter<<<2048, 256, 0, stream>>>(QKV, cosf, sinf, pos, Qr, Kall, outK, outV);
  build_vt<<<dim3(32, 8, 2), 256, 0, stream>>>(past_v, QKV, Vt);
  cvt_f32_bf16<<<8192, 256, 0, stream>>>(o_w, Wo, 16777216);  // after QKV consumed
  attn_fwd<<<1024, 256, 0, stream>>>(Qr, Kall, Vt, Ctx);
  gemm256<<<dim3(16, 8), 512, 0, stream>>>(Ctx, Wo, attn_out, 2048, 4096, 4096);
}

// Round 4
// 581.232 us; speedup vs baseline: 1.0746x; 1.0746x over previous
//
#include <hip/hip_runtime.h>
#include <hip/hip_bf16.h>
#include <stdint.h>

typedef __bf16 bf16_t;
typedef bf16_t bf16x8 __attribute__((ext_vector_type(8)));
typedef bf16_t bf16x4 __attribute__((ext_vector_type(4)));
typedef float f32x4 __attribute__((ext_vector_type(4)));

#define B_ 2
#define Q_ 1024
#define PAST_ 1024
#define T_ 2048
#define HID_ 4096
#define NH_ 32
#define NKV_ 8
#define HD_ 128
#define SCALE_ 0.08838834764831845f

__device__ __forceinline__ void async_cp16(const bf16_t* g, bf16_t* l) {
  __builtin_amdgcn_global_load_lds((__attribute__((address_space(1))) void*)g,
                                   (__attribute__((address_space(3))) void*)l, 16, 0, 0);
}

// ---------------- fp32 -> bf16 convert (8 elems/thread) ----------------
__global__ void cvt_f32_bf16(const float* __restrict__ src, bf16_t* __restrict__ dst, size_t n) {
  size_t i = ((size_t)blockIdx.x * blockDim.x + threadIdx.x) * 8;
  if (i >= n) return;
  float4 a = *(const float4*)(src + i);
  float4 b = *(const float4*)(src + i + 4);
  bf16x8 o;
  o[0] = (bf16_t)a.x; o[1] = (bf16_t)a.y; o[2] = (bf16_t)a.z; o[3] = (bf16_t)a.w;
  o[4] = (bf16_t)b.x; o[5] = (bf16_t)b.y; o[6] = (bf16_t)b.z; o[7] = (bf16_t)b.w;
  *(bf16x8*)(dst + i) = o;
}

// ---------------- past KV copy: fp32 -> d_out, bf16 K -> cache ----------------
__global__ void copy_past(const float* __restrict__ pk, const float* __restrict__ pv,
                          float* __restrict__ oK, float* __restrict__ oV,
                          bf16_t* __restrict__ Kall) {
  size_t i = ((size_t)blockIdx.x * 256 + threadIdx.x) * 4;
  if (i >= (size_t)B_ * NKV_ * PAST_ * HD_) return;
  int d = (int)(i & 127);
  size_t r = i >> 7;
  int t = (int)(r & 1023); r >>= 10;
  int g = (int)(r & 7); int b = (int)(r >> 3);
  size_t dst = (((size_t)b * NKV_ + g) * T_ + t) * HD_ + d;
  float4 k4 = *(const float4*)(pk + i);
  float4 v4 = *(const float4*)(pv + i);
  *(float4*)(oK + dst) = k4;
  *(float4*)(oV + dst) = v4;
  bf16x4 kb; kb[0] = (bf16_t)k4.x; kb[1] = (bf16_t)k4.y; kb[2] = (bf16_t)k4.z; kb[3] = (bf16_t)k4.w;
  *(bf16x4*)(Kall + dst) = kb;
}

// ---------------- build transposed V cache: Vt[b][g][d][t] bf16 ----------------
__global__ void build_vt(const float* __restrict__ past_v, const float* __restrict__ QKV,
                         bf16_t* __restrict__ Vt) {
  __shared__ bf16_t tile[64][136];
  const int tid = threadIdx.x;
  const int t0 = blockIdx.x * 64, g = blockIdx.y, b = blockIdx.z;
#pragma unroll
  for (int k = 0; k < 8; ++k) {
    int idx = k * 256 + tid;
    int t = idx >> 5, dc = (idx & 31) * 4;
    int tt = t0 + t;
    const float* src = (tt < PAST_)
        ? past_v + ((((size_t)b * NKV_ + g) * PAST_ + tt) * HD_ + dc)
        : QKV + (((size_t)b * Q_ + (tt - PAST_)) * 6144 + 5120 + g * HD_ + dc);
    float4 v4 = *(const float4*)src;
    tile[t][dc] = (bf16_t)v4.x; tile[t][dc + 1] = (bf16_t)v4.y;
    tile[t][dc + 2] = (bf16_t)v4.z; tile[t][dc + 3] = (bf16_t)v4.w;
  }
  __syncthreads();
#pragma unroll
  for (int k = 0; k < 4; ++k) {
    int idx = k * 256 + tid;
    int d = idx >> 3, c = idx & 7;
    bf16x8 o;
#pragma unroll
    for (int j = 0; j < 8; ++j) o[j] = tile[c * 8 + j][d];
    *(bf16x8*)(Vt + ((((size_t)b * NKV_ + g) * HD_ + d) * T_) + t0 + c * 8) = o;
  }
}

// ---------------- staging helpers (pre-swizzled global src, linear LDS dest) ----
__device__ __forceinline__ void stage_tile(const bf16_t* __restrict__ G, int ldg,
                                           bf16_t* __restrict__ L, int tid) {
#pragma unroll
  for (int t = 0; t < 4; ++t) {
    int c = t * 512 + tid;
    int row = c >> 3, sc = (c & 7) ^ (row & 7);
    int cb = t * 512 + (tid & 448);
    async_cp16(G + (size_t)row * ldg + sc * 8, L + (size_t)cb * 8);
  }
}

__device__ __forceinline__ void stage_tileA128(const bf16_t* __restrict__ G, int ldg,
                                               bf16_t* __restrict__ L, int tid) {
#pragma unroll
  for (int t = 0; t < 2; ++t) {
    int c = t * 512 + tid;
    int row = c >> 3, sc = (c & 7) ^ (row & 7);
    int cb = t * 512 + (tid & 448);
    async_cp16(G + (size_t)row * ldg + sc * 8, L + (size_t)cb * 8);
  }
}

// ---------------- 256x256 8-phase GEMM: C[M,N] = A[M,K] @ W[N,K]^T ----------------
__global__ __launch_bounds__(512, 2)
void gemm256(const bf16_t* __restrict__ A, const bf16_t* __restrict__ W,
             float* __restrict__ C, int M, int N, int K) {
  __shared__ bf16_t sm[2][2][16384];  // [buf][A|B][256*64]
  const int tid = threadIdx.x;
  const int lane = tid & 63;
  const int quad = lane >> 4, l15 = lane & 15;
  const int wave = tid >> 6;
  const int wm = wave >> 2, wn = wave & 3;
  const int bm = blockIdx.y * 256, bn = blockIdx.x * 256;
  const int NT = K >> 6;

  const bf16_t* Ag = A + (size_t)bm * K;
  const bf16_t* Wg = W + (size_t)bn * K;

  f32x4 acc[8][4] = {};

  stage_tile(Ag, K, &sm[0][0][0], tid);
  stage_tile(Wg, K, &sm[0][1][0], tid);
  stage_tile(Ag + 64, K, &sm[1][0][0], tid);
  stage_tile(Wg + 64, K, &sm[1][1][0], tid);
  asm volatile("s_waitcnt vmcnt(8)" ::: "memory");
  __builtin_amdgcn_s_barrier();

  const int arow = wm * 128 + l15;
  const int brow = wn * 64 + l15;
  const int pq = l15 & 7;

  for (int t = 0; t < NT; ++t) {
    const bf16_t* lA = &sm[t & 1][0][0];
    const bf16_t* lB = &sm[t & 1][1][0];
    const int k2 = (t + 2) << 6;
    bf16x8 af[4][2], bf01[2][2], bf23[2][2];

    // ---- P1 ----
#pragma unroll
    for (int m = 0; m < 4; ++m)
#pragma unroll
      for (int kk = 0; kk < 2; ++kk)
        af[m][kk] = *(const bf16x8*)(lA + (arow + m * 16) * 64 + ((((kk << 2) + quad) ^ pq) << 3));
#pragma unroll
    for (int n = 0; n < 2; ++n)
#pragma unroll
      for (int kk = 0; kk < 2; ++kk)
        bf01[n][kk] = *(const bf16x8*)(lB + (brow + n * 16) * 64 + ((((kk << 2) + quad) ^ pq) << 3));
    __builtin_amdgcn_s_barrier();
    asm volatile("s_waitcnt lgkmcnt(0)" ::: "memory");
    __builtin_amdgcn_sched_barrier(0);
    __builtin_amdgcn_s_setprio(1);
#pragma unroll
    for (int m = 0; m < 4; ++m)
#pragma unroll
      for (int n = 0; n < 2; ++n)
#pragma unroll
        for (int kk = 0; kk < 2; ++kk)
          acc[m][n] = __builtin_amdgcn_mfma_f32_16x16x32_bf16(af[m][kk], bf01[n][kk], acc[m][n], 0, 0, 0);
    __builtin_amdgcn_s_setprio(0);
    __builtin_amdgcn_s_barrier();

    // ---- P2 ----
#pragma unroll
    for (int n = 0; n < 2; ++n)
#pragma unroll
      for (int kk = 0; kk < 2; ++kk)
        bf23[n][kk] = *(const bf16x8*)(lB + (brow + (n + 2) * 16) * 64 + ((((kk << 2) + quad) ^ pq) << 3));
    __builtin_amdgcn_s_barrier();
    asm volatile("s_waitcnt lgkmcnt(0)" ::: "memory");
    __builtin_amdgcn_sched_barrier(0);
    __builtin_amdgcn_s_setprio(1);
#pragma unroll
    for (int m = 0; m < 4; ++m)
#pragma unroll
      for (int n = 0; n < 2; ++n)
#pragma unroll
        for (int kk = 0; kk < 2; ++kk)
          acc[m][n + 2] = __builtin_amdgcn_mfma_f32_16x16x32_bf16(af[m][kk], bf23[n][kk], acc[m][n + 2], 0, 0, 0);
    __builtin_amdgcn_s_setprio(0);
    __builtin_amdgcn_s_barrier();

    // ---- P3 ----
#pragma unroll
    for (int m = 0; m < 4; ++m)
#pragma unroll
      for (int kk = 0; kk < 2; ++kk)
        af[m][kk] = *(const bf16x8*)(lA + (arow + (m + 4) * 16) * 64 + ((((kk << 2) + quad) ^ pq) << 3));
    if (t + 2 < NT) stage_tile(Wg + k2, K, &sm[t & 1][1][0], tid);
    __builtin_amdgcn_s_barrier();
    asm volatile("s_waitcnt lgkmcnt(0)" ::: "memory");
    __builtin_amdgcn_sched_barrier(0);
    __builtin_amdgcn_s_setprio(1);
#pragma unroll
    for (int m = 0; m < 4; ++m)
#pragma unroll
      for (int n = 0; n < 2; ++n)
#pragma unroll
        for (int kk = 0; kk < 2; ++kk)
          acc[m + 4][n + 2] = __builtin_amdgcn_mfma_f32_16x16x32_bf16(af[m][kk], bf23[n][kk], acc[m + 4][n + 2], 0, 0, 0);
    __builtin_amdgcn_s_setprio(0);
    __builtin_amdgcn_s_barrier();

    // ---- P4 ----
    if (t + 2 < NT) stage_tile(Ag + k2, K, &sm[t & 1][0][0], tid);
    __builtin_amdgcn_s_barrier();
    __builtin_amdgcn_s_setprio(1);
#pragma unroll
    for (int m = 0; m < 4; ++m)
#pragma unroll
      for (int n = 0; n < 2; ++n)
#pragma unroll
        for (int kk = 0; kk < 2; ++kk)
          acc[m + 4][n] = __builtin_amdgcn_mfma_f32_16x16x32_bf16(af[m][kk], bf01[n][kk], acc[m + 4][n], 0, 0, 0);
    __builtin_amdgcn_s_setprio(0);
    if (t + 2 < NT)
      asm volatile("s_waitcnt vmcnt(8)" ::: "memory");
    else if (t + 2 == NT)
      asm volatile("s_waitcnt vmcnt(0)" ::: "memory");
    __builtin_amdgcn_s_barrier();
  }

#pragma unroll
  for (int m = 0; m < 8; ++m) {
    int row0 = bm + wm * 128 + m * 16 + quad * 4;
#pragma unroll
    for (int n = 0; n < 4; ++n) {
      int col = bn + wn * 64 + n * 16 + l15;
#pragma unroll
      for (int r = 0; r < 4; ++r)
        C[(size_t)(row0 + r) * N + col] = acc[m][n][r];
    }
  }
}

// ---------------- 128x256 4-phase GEMM (full-grid variant for out-proj) ----------
// Ledger: 6 loads/tile (B=4 in P3, A=2 in P4); steady vmcnt(6).
__global__ __launch_bounds__(512, 2)
void gemm128(const bf16_t* __restrict__ A, const bf16_t* __restrict__ W,
             float* __restrict__ C, int M, int N, int K) {
  __shared__ bf16_t smA[2][8192];   // 128 x 64
  __shared__ bf16_t smB[2][16384];  // 256 x 64
  const int tid = threadIdx.x;
  const int lane = tid & 63;
  const int quad = lane >> 4, l15 = lane & 15;
  const int wave = tid >> 6;
  const int wm = wave >> 2, wn = wave & 3;
  const int bm = blockIdx.y * 128, bn = blockIdx.x * 256;
  const int NT = K >> 6;

  const bf16_t* Ag = A + (size_t)bm * K;
  const bf16_t* Wg = W + (size_t)bn * K;

  f32x4 acc[4][4] = {};

  stage_tileA128(Ag, K, &smA[0][0], tid);
  stage_tile(Wg, K, &smB[0][0], tid);
  stage_tileA128(Ag + 64, K, &smA[1][0], tid);
  stage_tile(Wg + 64, K, &smB[1][0], tid);
  asm volatile("s_waitcnt vmcnt(6)" ::: "memory");
  __builtin_amdgcn_s_barrier();

  const int arow = wm * 64 + l15;
  const int brow = wn * 64 + l15;
  const int pq = l15 & 7;

  for (int t = 0; t < NT; ++t) {
    const bf16_t* lA = &smA[t & 1][0];
    const bf16_t* lB = &smB[t & 1][0];
    const int k2 = (t + 2) << 6;
    bf16x8 af[2][2], bf01[2][2], bf23[2][2];

    // ---- P1: A[m0-1], B[n0-1] -> acc[0..1][0..1] ----
#pragma unroll
    for (int m = 0; m < 2; ++m)
#pragma unroll
      for (int kk = 0; kk < 2; ++kk)
        af[m][kk] = *(const bf16x8*)(lA + (arow + m * 16) * 64 + ((((kk << 2) + quad) ^ pq) << 3));
#pragma unroll
    for (int n = 0; n < 2; ++n)
#pragma unroll
      for (int kk = 0; kk < 2; ++kk)
        bf01[n][kk] = *(const bf16x8*)(lB + (brow + n * 16) * 64 + ((((kk << 2) + quad) ^ pq) << 3));
    __builtin_amdgcn_s_barrier();
    asm volatile("s_waitcnt lgkmcnt(0)" ::: "memory");
    __builtin_amdgcn_sched_barrier(0);
    __builtin_amdgcn_s_setprio(1);
#pragma unroll
    for (int m = 0; m < 2; ++m)
#pragma unroll
      for (int n = 0; n < 2; ++n)
#pragma unroll
        for (int kk = 0; kk < 2; ++kk)
          acc[m][n] = __builtin_amdgcn_mfma_f32_16x16x32_bf16(af[m][kk], bf01[n][kk], acc[m][n], 0, 0, 0);
    __builtin_amdgcn_s_setprio(0);
    __builtin_amdgcn_s_barrier();

    // ---- P2: B[n2-3] -> acc[0..1][2..3] ----
#pragma unroll
    for (int n = 0; n < 2; ++n)
#pragma unroll
      for (int kk = 0; kk < 2; ++kk)
        bf23[n][kk] = *(const bf16x8*)(lB + (brow + (n + 2) * 16) * 64 + ((((kk << 2) + quad) ^ pq) << 3));
    __builtin_amdgcn_s_barrier();
    asm volatile("s_waitcnt lgkmcnt(0)" ::: "memory");
    __builtin_amdgcn_sched_barrier(0);
    __builtin_amdgcn_s_setprio(1);
#pragma unroll
    for (int m = 0; m < 2; ++m)
#pragma unroll
      for (int n = 0; n < 2; ++n)
#pragma unroll
        for (int kk = 0; kk < 2; ++kk)
          acc[m][n + 2] = __builtin_amdgcn_mfma_f32_16x16x32_bf16(af[m][kk], bf23[n][kk], acc[m][n + 2], 0, 0, 0);
    __builtin_amdgcn_s_setprio(0);
    __builtin_amdgcn_s_barrier();

    // ---- P3: A[m2-3]; stage B(t+2) -> acc[2..3][2..3] ----
#pragma unroll
    for (int m = 0; m < 2; ++m)
#pragma unroll
      for (int kk = 0; kk < 2; ++kk)
        af[m][kk] = *(const bf16x8*)(lA + (arow + (m + 2) * 16) * 64 + ((((kk << 2) + quad) ^ pq) << 3));
    if (t + 2 < NT) stage_tile(Wg + k2, K, &smB[t & 1][0], tid);
    __builtin_amdgcn_s_barrier();
    asm volatile("s_waitcnt lgkmcnt(0)" ::: "memory");
    __builtin_amdgcn_sched_barrier(0);
    __builtin_amdgcn_s_setprio(1);
#pragma unroll
    for (int m = 0; m < 2; ++m)
#pragma unroll
      for (int n = 0; n < 2; ++n)
#pragma unroll
        for (int kk = 0; kk < 2; ++kk)
          acc[m + 2][n + 2] = __builtin_amdgcn_mfma_f32_16x16x32_bf16(af[m][kk], bf23[n][kk], acc[m + 2][n + 2], 0, 0, 0);
    __builtin_amdgcn_s_setprio(0);
    __builtin_amdgcn_s_barrier();

    // ---- P4: stage A(t+2) -> acc[2..3][0..1]; counted drain ----
    if (t + 2 < NT) stage_tileA128(Ag + k2, K, &smA[t & 1][0], tid);
    __builtin_amdgcn_s_barrier();
    __builtin_amdgcn_s_setprio(1);
#pragma unroll
    for (int m = 0; m < 2; ++m)
#pragma unroll
      for (int n = 0; n < 2; ++n)
#pragma unroll
        for (int kk = 0; kk < 2; ++kk)
          acc[m + 2][n] = __builtin_amdgcn_mfma_f32_16x16x32_bf16(af[m][kk], bf01[n][kk], acc[m + 2][n], 0, 0, 0);
    __builtin_amdgcn_s_setprio(0);
    if (t + 2 < NT)
      asm volatile("s_waitcnt vmcnt(6)" ::: "memory");
    else if (t + 2 == NT)
      asm volatile("s_waitcnt vmcnt(0)" ::: "memory");
    __builtin_amdgcn_s_barrier();
  }

#pragma unroll
  for (int m = 0; m < 4; ++m) {
    int row0 = bm + wm * 64 + m * 16 + quad * 4;
#pragma unroll
    for (int n = 0; n < 4; ++n) {
      int col = bn + wn * 64 + n * 16 + l15;
#pragma unroll
      for (int r = 0; r < 4; ++r)
        C[(size_t)(row0 + r) * N + col] = acc[m][n][r];
    }
  }
}

// ---------------- RoPE + scatter ----------------
__global__ void rope_scatter(const float* __restrict__ QKV, const float* __restrict__ cosf,
                             const float* __restrict__ sinf, const int* __restrict__ pos_ids,
                             bf16_t* __restrict__ Qr, bf16_t* __restrict__ Kall,
                             float* __restrict__ outK, float* __restrict__ outV) {
  int m = blockIdx.x;
  int b = m >> 10, s = m & 1023;
  int pos = pos_ids[(size_t)b * Q_ + s];
  const float* row = QKV + (size_t)m * 6144;
  int tid = threadIdx.x;
  for (int p = tid; p < NH_ * 64; p += 256) {
    int h = p >> 6, d = p & 63;
    float x1 = row[h * 128 + d], x2 = row[h * 128 + d + 64];
    float c = cosf[pos * 64 + d], sn = sinf[pos * 64 + d];
    size_t qb = (((size_t)b * NH_ + h) * Q_ + s) * HD_;
    Qr[qb + d] = (bf16_t)(x1 * c - x2 * sn);
    Qr[qb + d + 64] = (bf16_t)(x2 * c + x1 * sn);
  }
  for (int p = tid; p < NKV_ * 64; p += 256) {
    int g = p >> 6, d = p & 63;
    float x1 = row[4096 + g * 128 + d], x2 = row[4096 + g * 128 + d + 64];
    float c = cosf[pos * 64 + d], sn = sinf[pos * 64 + d];
    float o1 = x1 * c - x2 * sn, o2 = x2 * c + x1 * sn;
    size_t kbi = (((size_t)b * NKV_ + g) * T_ + PAST_ + s) * HD_;
    Kall[kbi + d] = (bf16_t)o1; Kall[kbi + d + 64] = (bf16_t)o2;
    outK[kbi + d] = o1; outK[kbi + d + 64] = o2;
  }
  for (int e = tid; e < NKV_ * HD_; e += 256) {
    int g = e >> 7, d = e & 127;
    float v = row[5120 + g * 128 + d];
    outV[(((size_t)b * NKV_ + g) * T_ + PAST_ + s) * HD_ + d] = v;
  }
}

// ---------------- flash attention (pipelined: dbuf K/V + counted vmcnt) ----------
// LDS 72 KiB -> 2 blocks/CU. Tile t+1's 8 gload_lds stay in flight across the
// barrier while tile t is computed (counted vmcnt(8), raw s_barrier, no drain).
__global__ __launch_bounds__(256, 2)
void attn_fwd(const bf16_t* __restrict__ Qr, const bf16_t* __restrict__ Kall,
              const bf16_t* __restrict__ Vt, bf16_t* __restrict__ Ctx) {
  __shared__ bf16_t lK[2][64 * 128];
  __shared__ bf16_t lV[2][128 * 64];
  __shared__ bf16_t lP[4 * 16 * 64];
  const int tid = threadIdx.x;
  const int wave = tid >> 6, lane = tid & 63;
  const int quad = lane >> 4, l15 = lane & 15;
  const int i = blockIdx.x;
  const int xcd = i & 7;
  const int j = i >> 3;
  const int pairsel = j & 1;
  const int idx = j >> 1;
  const int h_in = idx & 3;
  const int qt = 15 - (idx >> 2);  // heavy first
  const int b = pairsel, kv = xcd;
  const int h = kv * 4 + h_in;
  const int qbase = qt * 64;
  const int wq = qbase + wave * 16;
  const size_t kvbase = ((size_t)b * NKV_ + kv) * T_ * HD_;
  const size_t vtbase = ((size_t)b * NKV_ + kv) * HD_ * T_;

  auto stageKV = [&](int kb, int s) {
#pragma unroll
    for (int t = 0; t < 4; ++t) {
      int cb = t * 256 + wave * 64;
      int c = cb + lane;
      int row = c >> 4, sc = (c & 15) ^ (row & 15);
      async_cp16(Kall + kvbase + (size_t)(kb + row) * HD_ + sc * 8, lK[s] + (size_t)cb * 8);
    }
#pragma unroll
    for (int t = 0; t < 4; ++t) {
      int cb = t * 256 + wave * 64;
      int c = cb + lane;
      int d = c >> 3, sc = (c & 7) ^ (d & 7);
      async_cp16(Vt + vtbase + (size_t)d * T_ + kb + sc * 8, lV[s] + (size_t)cb * 8);
    }
  };

  bf16x8 qf[4];
  {
    const bf16_t* qg = Qr + ((((size_t)b * NH_ + h) * Q_) + wq + l15) * HD_ + quad * 8;
#pragma unroll
    for (int kk = 0; kk < 4; ++kk) qf[kk] = *(const bf16x8*)(qg + kk * 32);
  }
  f32x4 ctx[8] = {};
  float Mr[4], Lr[4];
#pragma unroll
  for (int r = 0; r < 4; ++r) { Mr[r] = -3.0e30f; Lr[r] = 0.0f; }
  bf16_t* lPw = lP + wave * 16 * 64;
  const int nt = (PAST_ + qbase + 64) >> 6;
  const int wlimit = PAST_ + wq + 15;

  stageKV(0, 0);  // prologue: tile 0 in flight

  for (int ti = 0; ti < nt; ++ti) {
    const int kb = ti << 6;
    const int cur = ti & 1;
    if (ti + 1 < nt) {
      stageKV(kb + 64, cur ^ 1);
      asm volatile("s_waitcnt vmcnt(8)" ::: "memory");  // tile ti landed; ti+1 in flight
    } else {
      asm volatile("s_waitcnt vmcnt(0)" ::: "memory");
    }
    __builtin_amdgcn_s_barrier();
    asm volatile("" ::: "memory");
    if (kb <= wlimit) {
      const bf16_t* cK = lK[cur];
      const bf16_t* cV = lV[cur];
      f32x4 sacc[4];
#pragma unroll
      for (int nc = 0; nc < 4; ++nc) sacc[nc] = (f32x4){0.f, 0.f, 0.f, 0.f};
      __builtin_amdgcn_s_setprio(1);
#pragma unroll
      for (int nc = 0; nc < 4; ++nc)
#pragma unroll
        for (int kk = 0; kk < 4; ++kk) {
          bf16x8 bk = *(const bf16x8*)(cK + (nc * 16 + l15) * 128 + (((kk * 4 + quad) ^ l15) << 3));
          sacc[nc] = __builtin_amdgcn_mfma_f32_16x16x32_bf16(qf[kk], bk, sacc[nc], 0, 0, 0);
        }
      __builtin_amdgcn_s_setprio(0);
      bool fullvis = (kb + 63 <= PAST_ + wq);
#pragma unroll
      for (int nc = 0; nc < 4; ++nc) {
        int tkey = kb + nc * 16 + l15;
#pragma unroll
        for (int r = 0; r < 4; ++r) {
          float val = sacc[nc][r] * SCALE_;
          if (!fullvis && tkey > PAST_ + wq + quad * 4 + r) val -= 10000.0f;
          sacc[nc][r] = val;
        }
      }
      float alpha[4], rs[4] = {};
#pragma unroll
      for (int r = 0; r < 4; ++r) {
        float tm = fmaxf(fmaxf(sacc[0][r], sacc[1][r]), fmaxf(sacc[2][r], sacc[3][r]));
#pragma unroll
        for (int mmk = 1; mmk < 16; mmk <<= 1) tm = fmaxf(tm, __shfl_xor(tm, mmk, 64));
        float nm = fmaxf(Mr[r], tm);
        alpha[r] = __expf(Mr[r] - nm);
        Mr[r] = nm;
      }
#pragma unroll
      for (int nc = 0; nc < 4; ++nc)
#pragma unroll
        for (int r = 0; r < 4; ++r) {
          float p = __expf(sacc[nc][r] - Mr[r]);
          rs[r] += p;
          int rho = quad * 4 + r;
          int cslot = ((nc * 2 + (l15 >> 3)) ^ (rho & 7));
          lPw[rho * 64 + cslot * 8 + (l15 & 7)] = (bf16_t)p;
        }
#pragma unroll
      for (int r = 0; r < 4; ++r) {
        float s = rs[r];
#pragma unroll
        for (int mmk = 1; mmk < 16; mmk <<= 1) s += __shfl_xor(s, mmk, 64);
        Lr[r] = Lr[r] * alpha[r] + s;
      }
#pragma unroll
      for (int nc2 = 0; nc2 < 8; ++nc2)
#pragma unroll
        for (int r = 0; r < 4; ++r) ctx[nc2][r] *= alpha[r];
      asm volatile("s_waitcnt lgkmcnt(0)" ::: "memory");
      __builtin_amdgcn_sched_barrier(0);
      __builtin_amdgcn_s_setprio(1);
#pragma unroll
      for (int kk2 = 0; kk2 < 2; ++kk2) {
        bf16x8 ap = *(const bf16x8*)(lPw + l15 * 64 + (((kk2 * 4 + quad) ^ (l15 & 7)) << 3));
#pragma unroll
        for (int nc2 = 0; nc2 < 8; ++nc2) {
          bf16x8 bv = *(const bf16x8*)(cV + (nc2 * 16 + l15) * 64 + (((kk2 * 4 + quad) ^ (l15 & 7)) << 3));
          ctx[nc2] = __builtin_amdgcn_mfma_f32_16x16x32_bf16(ap, bv, ctx[nc2], 0, 0, 0);
        }
      }
      __builtin_amdgcn_s_setprio(0);
    }
    __builtin_amdgcn_sched_barrier(0);
    __builtin_amdgcn_s_barrier();
  }
  float inv[4];
#pragma unroll
  for (int r = 0; r < 4; ++r) inv[r] = 1.0f / Lr[r];
#pragma unroll
  for (int nc2 = 0; nc2 < 8; ++nc2)
#pragma unroll
    for (int r = 0; r < 4; ++r) {
      size_t row = (size_t)b * Q_ + wq + quad * 4 + r;
      Ctx[row * (NH_ * HD_) + h * HD_ + nc2 * 16 + l15] = (bf16_t)(ctx[nc2][r] * inv[r]);
    }
}

extern "C" void kernel_launch(void* const* d_in, const int* in_sizes, int n_in,
                              void* d_out, int out_size, void* d_ws, size_t ws_size,
                              hipStream_t stream) {
  const float* hidden = (const float*)d_in[0];
  const int* pos = (const int*)d_in[2];
  const float* cosf = (const float*)d_in[3];
  const float* sinf = (const float*)d_in[4];
  const float* past_k = (const float*)d_in[5];
  const float* past_v = (const float*)d_in[6];
  const float* q_w = (const float*)d_in[7];
  const float* k_w = (const float*)d_in[8];
  const float* v_w = (const float*)d_in[9];
  const float* o_w = (const float*)d_in[10];

  float* attn_out = (float*)d_out;
  float* outK = attn_out + (size_t)B_ * Q_ * HID_;
  float* outV = outK + (size_t)B_ * NKV_ * T_ * HD_;

  if (ws_size < 150994944) return;
  char* ws = (char*)d_ws;
  bf16_t* Wqkv = (bf16_t*)(ws);              // 48 MiB
  bf16_t* Xb   = (bf16_t*)(ws + 50331648);   // 16 MiB
  float*  QKV  = (float*)(ws + 67108864);    // 48 MiB
  bf16_t* Qr   = (bf16_t*)(ws + 117440512);  // 16 MiB
  bf16_t* Kall = (bf16_t*)(ws + 134217728);  // 8 MiB
  bf16_t* Vt   = (bf16_t*)(ws + 142606336);  // 8 MiB (d-major transposed V)
  bf16_t* Wo   = (bf16_t*)(ws + 67108864);   // alias QKV (converted after build_vt)
  bf16_t* Ctx  = (bf16_t*)(ws + 50331648);   // alias Xb (written after gemm1)

  cvt_f32_bf16<<<4096, 256, 0, stream>>>(hidden, Xb, 8388608);
  cvt_f32_bf16<<<8192, 256, 0, stream>>>(q_w, Wqkv, 16777216);
  cvt_f32_bf16<<<2048, 256, 0, stream>>>(k_w, Wqkv + 16777216, 4194304);
  cvt_f32_bf16<<<2048, 256, 0, stream>>>(v_w, Wqkv + 20971520, 4194304);
  copy_past<<<2048, 256, 0, stream>>>(past_k, past_v, outK, outV, Kall);
  gemm256<<<dim3(24, 8), 512, 0, stream>>>(Xb, Wqkv, QKV, 2048, 6144, 4096);
  rope_scatter<<<2048, 256, 0, stream>>>(QKV, cosf, sinf, pos, Qr, Kall, outK, outV);
  build_vt<<<dim3(32, 8, 2), 256, 0, stream>>>(past_v, QKV, Vt);
  cvt_f32_bf16<<<8192, 256, 0, stream>>>(o_w, Wo, 16777216);  // after QKV consumed
  attn_fwd<<<1024, 256, 0, stream>>>(Qr, Kall, Vt, Ctx);
  gemm128<<<dim3(16, 16), 512, 0, stream>>>(Ctx, Wo, attn_out, 2048, 4096, 4096);
}

// Round 6
// 580.739 us; speedup vs baseline: 1.0755x; 1.0008x over previous
//
#include <hip/hip_runtime.h>
#include <hip/hip_bf16.h>
#include <stdint.h>

typedef __bf16 bf16_t;
typedef bf16_t bf16x8 __attribute__((ext_vector_type(8)));
typedef bf16_t bf16x4 __attribute__((ext_vector_type(4)));
typedef float f32x4 __attribute__((ext_vector_type(4)));

#define B_ 2
#define Q_ 1024
#define PAST_ 1024
#define T_ 2048
#define HID_ 4096
#define NH_ 32
#define NKV_ 8
#define HD_ 128
#define SCALE_ 0.08838834764831845f

__device__ __forceinline__ void async_cp16(const bf16_t* g, bf16_t* l) {
  __builtin_amdgcn_global_load_lds((__attribute__((address_space(1))) void*)g,
                                   (__attribute__((address_space(3))) void*)l, 16, 0, 0);
}

// ---------------- fp32 -> bf16 convert (8 elems/thread) ----------------
__global__ void cvt_f32_bf16(const float* __restrict__ src, bf16_t* __restrict__ dst, size_t n) {
  size_t i = ((size_t)blockIdx.x * blockDim.x + threadIdx.x) * 8;
  if (i >= n) return;
  float4 a = *(const float4*)(src + i);
  float4 b = *(const float4*)(src + i + 4);
  bf16x8 o;
  o[0] = (bf16_t)a.x; o[1] = (bf16_t)a.y; o[2] = (bf16_t)a.z; o[3] = (bf16_t)a.w;
  o[4] = (bf16_t)b.x; o[5] = (bf16_t)b.y; o[6] = (bf16_t)b.z; o[7] = (bf16_t)b.w;
  *(bf16x8*)(dst + i) = o;
}

// ---------------- past KV copy: fp32 -> d_out, bf16 K -> cache ----------------
__global__ void copy_past(const float* __restrict__ pk, const float* __restrict__ pv,
                          float* __restrict__ oK, float* __restrict__ oV,
                          bf16_t* __restrict__ Kall) {
  size_t i = ((size_t)blockIdx.x * 256 + threadIdx.x) * 4;
  if (i >= (size_t)B_ * NKV_ * PAST_ * HD_) return;
  int d = (int)(i & 127);
  size_t r = i >> 7;
  int t = (int)(r & 1023); r >>= 10;
  int g = (int)(r & 7); int b = (int)(r >> 3);
  size_t dst = (((size_t)b * NKV_ + g) * T_ + t) * HD_ + d;
  float4 k4 = *(const float4*)(pk + i);
  float4 v4 = *(const float4*)(pv + i);
  *(float4*)(oK + dst) = k4;
  *(float4*)(oV + dst) = v4;
  bf16x4 kb; kb[0] = (bf16_t)k4.x; kb[1] = (bf16_t)k4.y; kb[2] = (bf16_t)k4.z; kb[3] = (bf16_t)k4.w;
  *(bf16x4*)(Kall + dst) = kb;
}

// ---------------- build transposed V cache: Vt[b][g][d][t] bf16 ----------------
__global__ void build_vt(const float* __restrict__ past_v, const float* __restrict__ QKV,
                         bf16_t* __restrict__ Vt) {
  __shared__ bf16_t tile[64][136];
  const int tid = threadIdx.x;
  const int t0 = blockIdx.x * 64, g = blockIdx.y, b = blockIdx.z;
#pragma unroll
  for (int k = 0; k < 8; ++k) {
    int idx = k * 256 + tid;
    int t = idx >> 5, dc = (idx & 31) * 4;
    int tt = t0 + t;
    const float* src = (tt < PAST_)
        ? past_v + ((((size_t)b * NKV_ + g) * PAST_ + tt) * HD_ + dc)
        : QKV + (((size_t)b * Q_ + (tt - PAST_)) * 6144 + 5120 + g * HD_ + dc);
    float4 v4 = *(const float4*)src;
    tile[t][dc] = (bf16_t)v4.x; tile[t][dc + 1] = (bf16_t)v4.y;
    tile[t][dc + 2] = (bf16_t)v4.z; tile[t][dc + 3] = (bf16_t)v4.w;
  }
  __syncthreads();
#pragma unroll
  for (int k = 0; k < 4; ++k) {
    int idx = k * 256 + tid;
    int d = idx >> 3, c = idx & 7;
    bf16x8 o;
#pragma unroll
    for (int j = 0; j < 8; ++j) o[j] = tile[c * 8 + j][d];
    *(bf16x8*)(Vt + ((((size_t)b * NKV_ + g) * HD_ + d) * T_) + t0 + c * 8) = o;
  }
}

// ---------------- staging helpers (pre-swizzled global src, linear LDS dest) ----
__device__ __forceinline__ void stage_tile(const bf16_t* __restrict__ G, int ldg,
                                           bf16_t* __restrict__ L, int tid) {
#pragma unroll
  for (int t = 0; t < 4; ++t) {
    int c = t * 512 + tid;
    int row = c >> 3, sc = (c & 7) ^ (row & 7);
    int cb = t * 512 + (tid & 448);
    async_cp16(G + (size_t)row * ldg + sc * 8, L + (size_t)cb * 8);
  }
}

__device__ __forceinline__ void stage_tileA128(const bf16_t* __restrict__ G, int ldg,
                                               bf16_t* __restrict__ L, int tid) {
#pragma unroll
  for (int t = 0; t < 2; ++t) {
    int c = t * 512 + tid;
    int row = c >> 3, sc = (c & 7) ^ (row & 7);
    int cb = t * 512 + (tid & 448);
    async_cp16(G + (size_t)row * ldg + sc * 8, L + (size_t)cb * 8);
  }
}

// ---------------- 256x256 8-phase GEMM: C[M,N] = A[M,K] @ W[N,K]^T ----------------
__global__ __launch_bounds__(512, 2)
void gemm256(const bf16_t* __restrict__ A, const bf16_t* __restrict__ W,
             float* __restrict__ C, int M, int N, int K) {
  __shared__ bf16_t sm[2][2][16384];  // [buf][A|B][256*64]
  const int tid = threadIdx.x;
  const int lane = tid & 63;
  const int quad = lane >> 4, l15 = lane & 15;
  const int wave = tid >> 6;
  const int wm = wave >> 2, wn = wave & 3;
  const int bm = blockIdx.y * 256, bn = blockIdx.x * 256;
  const int NT = K >> 6;

  const bf16_t* Ag = A + (size_t)bm * K;
  const bf16_t* Wg = W + (size_t)bn * K;

  f32x4 acc[8][4] = {};

  stage_tile(Ag, K, &sm[0][0][0], tid);
  stage_tile(Wg, K, &sm[0][1][0], tid);
  stage_tile(Ag + 64, K, &sm[1][0][0], tid);
  stage_tile(Wg + 64, K, &sm[1][1][0], tid);
  asm volatile("s_waitcnt vmcnt(8)" ::: "memory");
  __builtin_amdgcn_s_barrier();

  const int arow = wm * 128 + l15;
  const int brow = wn * 64 + l15;
  const int pq = l15 & 7;

  for (int t = 0; t < NT; ++t) {
    const bf16_t* lA = &sm[t & 1][0][0];
    const bf16_t* lB = &sm[t & 1][1][0];
    const int k2 = (t + 2) << 6;
    bf16x8 af[4][2], bf01[2][2], bf23[2][2];

    // ---- P1 ----
#pragma unroll
    for (int m = 0; m < 4; ++m)
#pragma unroll
      for (int kk = 0; kk < 2; ++kk)
        af[m][kk] = *(const bf16x8*)(lA + (arow + m * 16) * 64 + ((((kk << 2) + quad) ^ pq) << 3));
#pragma unroll
    for (int n = 0; n < 2; ++n)
#pragma unroll
      for (int kk = 0; kk < 2; ++kk)
        bf01[n][kk] = *(const bf16x8*)(lB + (brow + n * 16) * 64 + ((((kk << 2) + quad) ^ pq) << 3));
    __builtin_amdgcn_s_barrier();
    asm volatile("s_waitcnt lgkmcnt(0)" ::: "memory");
    __builtin_amdgcn_sched_barrier(0);
    __builtin_amdgcn_s_setprio(1);
#pragma unroll
    for (int m = 0; m < 4; ++m)
#pragma unroll
      for (int n = 0; n < 2; ++n)
#pragma unroll
        for (int kk = 0; kk < 2; ++kk)
          acc[m][n] = __builtin_amdgcn_mfma_f32_16x16x32_bf16(af[m][kk], bf01[n][kk], acc[m][n], 0, 0, 0);
    __builtin_amdgcn_s_setprio(0);
    __builtin_amdgcn_s_barrier();

    // ---- P2 ----
#pragma unroll
    for (int n = 0; n < 2; ++n)
#pragma unroll
      for (int kk = 0; kk < 2; ++kk)
        bf23[n][kk] = *(const bf16x8*)(lB + (brow + (n + 2) * 16) * 64 + ((((kk << 2) + quad) ^ pq) << 3));
    __builtin_amdgcn_s_barrier();
    asm volatile("s_waitcnt lgkmcnt(0)" ::: "memory");
    __builtin_amdgcn_sched_barrier(0);
    __builtin_amdgcn_s_setprio(1);
#pragma unroll
    for (int m = 0; m < 4; ++m)
#pragma unroll
      for (int n = 0; n < 2; ++n)
#pragma unroll
        for (int kk = 0; kk < 2; ++kk)
          acc[m][n + 2] = __builtin_amdgcn_mfma_f32_16x16x32_bf16(af[m][kk], bf23[n][kk], acc[m][n + 2], 0, 0, 0);
    __builtin_amdgcn_s_setprio(0);
    __builtin_amdgcn_s_barrier();

    // ---- P3 ----
#pragma unroll
    for (int m = 0; m < 4; ++m)
#pragma unroll
      for (int kk = 0; kk < 2; ++kk)
        af[m][kk] = *(const bf16x8*)(lA + (arow + (m + 4) * 16) * 64 + ((((kk << 2) + quad) ^ pq) << 3));
    if (t + 2 < NT) stage_tile(Wg + k2, K, &sm[t & 1][1][0], tid);
    __builtin_amdgcn_s_barrier();
    asm volatile("s_waitcnt lgkmcnt(0)" ::: "memory");
    __builtin_amdgcn_sched_barrier(0);
    __builtin_amdgcn_s_setprio(1);
#pragma unroll
    for (int m = 0; m < 4; ++m)
#pragma unroll
      for (int n = 0; n < 2; ++n)
#pragma unroll
        for (int kk = 0; kk < 2; ++kk)
          acc[m + 4][n + 2] = __builtin_amdgcn_mfma_f32_16x16x32_bf16(af[m][kk], bf23[n][kk], acc[m + 4][n + 2], 0, 0, 0);
    __builtin_amdgcn_s_setprio(0);
    __builtin_amdgcn_s_barrier();

    // ---- P4 ----
    if (t + 2 < NT) stage_tile(Ag + k2, K, &sm[t & 1][0][0], tid);
    __builtin_amdgcn_s_barrier();
    __builtin_amdgcn_s_setprio(1);
#pragma unroll
    for (int m = 0; m < 4; ++m)
#pragma unroll
      for (int n = 0; n < 2; ++n)
#pragma unroll
        for (int kk = 0; kk < 2; ++kk)
          acc[m + 4][n] = __builtin_amdgcn_mfma_f32_16x16x32_bf16(af[m][kk], bf01[n][kk], acc[m + 4][n], 0, 0, 0);
    __builtin_amdgcn_s_setprio(0);
    if (t + 2 < NT)
      asm volatile("s_waitcnt vmcnt(8)" ::: "memory");
    else if (t + 2 == NT)
      asm volatile("s_waitcnt vmcnt(0)" ::: "memory");
    __builtin_amdgcn_s_barrier();
  }

#pragma unroll
  for (int m = 0; m < 8; ++m) {
    int row0 = bm + wm * 128 + m * 16 + quad * 4;
#pragma unroll
    for (int n = 0; n < 4; ++n) {
      int col = bn + wn * 64 + n * 16 + l15;
#pragma unroll
      for (int r = 0; r < 4; ++r)
        C[(size_t)(row0 + r) * N + col] = acc[m][n][r];
    }
  }
}

// ---------------- 128x256 4-phase GEMM (full-grid variant for out-proj) ----------
__global__ __launch_bounds__(512, 2)
void gemm128(const bf16_t* __restrict__ A, const bf16_t* __restrict__ W,
             float* __restrict__ C, int M, int N, int K) {
  __shared__ bf16_t smA[2][8192];   // 128 x 64
  __shared__ bf16_t smB[2][16384];  // 256 x 64
  const int tid = threadIdx.x;
  const int lane = tid & 63;
  const int quad = lane >> 4, l15 = lane & 15;
  const int wave = tid >> 6;
  const int wm = wave >> 2, wn = wave & 3;
  const int bm = blockIdx.y * 128, bn = blockIdx.x * 256;
  const int NT = K >> 6;

  const bf16_t* Ag = A + (size_t)bm * K;
  const bf16_t* Wg = W + (size_t)bn * K;

  f32x4 acc[4][4] = {};

  stage_tileA128(Ag, K, &smA[0][0], tid);
  stage_tile(Wg, K, &smB[0][0], tid);
  stage_tileA128(Ag + 64, K, &smA[1][0], tid);
  stage_tile(Wg + 64, K, &smB[1][0], tid);
  asm volatile("s_waitcnt vmcnt(6)" ::: "memory");
  __builtin_amdgcn_s_barrier();

  const int arow = wm * 64 + l15;
  const int brow = wn * 64 + l15;
  const int pq = l15 & 7;

  for (int t = 0; t < NT; ++t) {
    const bf16_t* lA = &smA[t & 1][0];
    const bf16_t* lB = &smB[t & 1][0];
    const int k2 = (t + 2) << 6;
    bf16x8 af[2][2], bf01[2][2], bf23[2][2];

    // ---- P1 ----
#pragma unroll
    for (int m = 0; m < 2; ++m)
#pragma unroll
      for (int kk = 0; kk < 2; ++kk)
        af[m][kk] = *(const bf16x8*)(lA + (arow + m * 16) * 64 + ((((kk << 2) + quad) ^ pq) << 3));
#pragma unroll
    for (int n = 0; n < 2; ++n)
#pragma unroll
      for (int kk = 0; kk < 2; ++kk)
        bf01[n][kk] = *(const bf16x8*)(lB + (brow + n * 16) * 64 + ((((kk << 2) + quad) ^ pq) << 3));
    __builtin_amdgcn_s_barrier();
    asm volatile("s_waitcnt lgkmcnt(0)" ::: "memory");
    __builtin_amdgcn_sched_barrier(0);
    __builtin_amdgcn_s_setprio(1);
#pragma unroll
    for (int m = 0; m < 2; ++m)
#pragma unroll
      for (int n = 0; n < 2; ++n)
#pragma unroll
        for (int kk = 0; kk < 2; ++kk)
          acc[m][n] = __builtin_amdgcn_mfma_f32_16x16x32_bf16(af[m][kk], bf01[n][kk], acc[m][n], 0, 0, 0);
    __builtin_amdgcn_s_setprio(0);
    __builtin_amdgcn_s_barrier();

    // ---- P2 ----
#pragma unroll
    for (int n = 0; n < 2; ++n)
#pragma unroll
      for (int kk = 0; kk < 2; ++kk)
        bf23[n][kk] = *(const bf16x8*)(lB + (brow + (n + 2) * 16) * 64 + ((((kk << 2) + quad) ^ pq) << 3));
    __builtin_amdgcn_s_barrier();
    asm volatile("s_waitcnt lgkmcnt(0)" ::: "memory");
    __builtin_amdgcn_sched_barrier(0);
    __builtin_amdgcn_s_setprio(1);
#pragma unroll
    for (int m = 0; m < 2; ++m)
#pragma unroll
      for (int n = 0; n < 2; ++n)
#pragma unroll
        for (int kk = 0; kk < 2; ++kk)
          acc[m][n + 2] = __builtin_amdgcn_mfma_f32_16x16x32_bf16(af[m][kk], bf23[n][kk], acc[m][n + 2], 0, 0, 0);
    __builtin_amdgcn_s_setprio(0);
    __builtin_amdgcn_s_barrier();

    // ---- P3 ----
#pragma unroll
    for (int m = 0; m < 2; ++m)
#pragma unroll
      for (int kk = 0; kk < 2; ++kk)
        af[m][kk] = *(const bf16x8*)(lA + (arow + (m + 2) * 16) * 64 + ((((kk << 2) + quad) ^ pq) << 3));
    if (t + 2 < NT) stage_tile(Wg + k2, K, &smB[t & 1][0], tid);
    __builtin_amdgcn_s_barrier();
    asm volatile("s_waitcnt lgkmcnt(0)" ::: "memory");
    __builtin_amdgcn_sched_barrier(0);
    __builtin_amdgcn_s_setprio(1);
#pragma unroll
    for (int m = 0; m < 2; ++m)
#pragma unroll
      for (int n = 0; n < 2; ++n)
#pragma unroll
        for (int kk = 0; kk < 2; ++kk)
          acc[m + 2][n + 2] = __builtin_amdgcn_mfma_f32_16x16x32_bf16(af[m][kk], bf23[n][kk], acc[m + 2][n + 2], 0, 0, 0);
    __builtin_amdgcn_s_setprio(0);
    __builtin_amdgcn_s_barrier();

    // ---- P4 ----
    if (t + 2 < NT) stage_tileA128(Ag + k2, K, &smA[t & 1][0], tid);
    __builtin_amdgcn_s_barrier();
    __builtin_amdgcn_s_setprio(1);
#pragma unroll
    for (int m = 0; m < 2; ++m)
#pragma unroll
      for (int n = 0; n < 2; ++n)
#pragma unroll
        for (int kk = 0; kk < 2; ++kk)
          acc[m + 2][n] = __builtin_amdgcn_mfma_f32_16x16x32_bf16(af[m][kk], bf01[n][kk], acc[m + 2][n], 0, 0, 0);
    __builtin_amdgcn_s_setprio(0);
    if (t + 2 < NT)
      asm volatile("s_waitcnt vmcnt(6)" ::: "memory");
    else if (t + 2 == NT)
      asm volatile("s_waitcnt vmcnt(0)" ::: "memory");
    __builtin_amdgcn_s_barrier();
  }

#pragma unroll
  for (int m = 0; m < 4; ++m) {
    int row0 = bm + wm * 64 + m * 16 + quad * 4;
#pragma unroll
    for (int n = 0; n < 4; ++n) {
      int col = bn + wn * 64 + n * 16 + l15;
#pragma unroll
      for (int r = 0; r < 4; ++r)
        C[(size_t)(row0 + r) * N + col] = acc[m][n][r];
    }
  }
}

// ---------------- RoPE + scatter (Q pre-scaled by SCALE for attn) ----------------
__global__ void rope_scatter(const float* __restrict__ QKV, const float* __restrict__ cosf,
                             const float* __restrict__ sinf, const int* __restrict__ pos_ids,
                             bf16_t* __restrict__ Qr, bf16_t* __restrict__ Kall,
                             float* __restrict__ outK, float* __restrict__ outV) {
  int m = blockIdx.x;
  int b = m >> 10, s = m & 1023;
  int pos = pos_ids[(size_t)b * Q_ + s];
  const float* row = QKV + (size_t)m * 6144;
  int tid = threadIdx.x;
  for (int p = tid; p < NH_ * 64; p += 256) {
    int h = p >> 6, d = p & 63;
    float x1 = row[h * 128 + d], x2 = row[h * 128 + d + 64];
    float c = cosf[pos * 64 + d], sn = sinf[pos * 64 + d];
    size_t qb = (((size_t)b * NH_ + h) * Q_ + s) * HD_;
    Qr[qb + d] = (bf16_t)((x1 * c - x2 * sn) * SCALE_);
    Qr[qb + d + 64] = (bf16_t)((x2 * c + x1 * sn) * SCALE_);
  }
  for (int p = tid; p < NKV_ * 64; p += 256) {
    int g = p >> 6, d = p & 63;
    float x1 = row[4096 + g * 128 + d], x2 = row[4096 + g * 128 + d + 64];
    float c = cosf[pos * 64 + d], sn = sinf[pos * 64 + d];
    float o1 = x1 * c - x2 * sn, o2 = x2 * c + x1 * sn;
    size_t kbi = (((size_t)b * NKV_ + g) * T_ + PAST_ + s) * HD_;
    Kall[kbi + d] = (bf16_t)o1; Kall[kbi + d + 64] = (bf16_t)o2;
    outK[kbi + d] = o1; outK[kbi + d + 64] = o2;
  }
  for (int e = tid; e < NKV_ * HD_; e += 256) {
    int g = e >> 7, d = e & 127;
    float v = row[5120 + g * 128 + d];
    outV[(((size_t)b * NKV_ + g) * T_ + PAST_ + s) * HD_ + d] = v;
  }
}

// ---------------- flash attention (8 waves/block, QBLK=128, dbuf + counted vmcnt) --
// Grid 512 = 2 blocks/CU (16 waves/CU = 4/SIMD). LDS 80 KiB: lK dbuf 32K +
// lV dbuf 32K + lP 16K. Ledger: 4 gload_lds/thread/stage -> steady vmcnt(4).
// Q pre-scaled by SCALE in rope_scatter. Defer-max (THR=8) skips ctx rescale.
__global__ __launch_bounds__(512, 2)
void attn_fwd(const bf16_t* __restrict__ Qr, const bf16_t* __restrict__ Kall,
              const bf16_t* __restrict__ Vt, bf16_t* __restrict__ Ctx) {
  __shared__ bf16_t lK[2][64 * 128];
  __shared__ bf16_t lV[2][128 * 64];
  __shared__ bf16_t lP[8 * 16 * 64];
  const int tid = threadIdx.x;
  const int wave = tid >> 6, lane = tid & 63;
  const int quad = lane >> 4, l15 = lane & 15;
  const int i = blockIdx.x;
  const int xcd = i & 7;
  const int j = i >> 3;
  const int pairsel = j & 1;
  const int idx = j >> 1;          // 0..31
  const int h_in = idx & 3;
  const int qt = 7 - (idx >> 2);   // heavy first (8 q-tiles of 128 rows)
  const int b = pairsel, kv = xcd;
  const int h = kv * 4 + h_in;
  const int qbase = qt * 128;
  const int wq = qbase + wave * 16;
  const size_t kvbase = ((size_t)b * NKV_ + kv) * T_ * HD_;
  const size_t vtbase = ((size_t)b * NKV_ + kv) * HD_ * T_;

  auto stageKV = [&](int kb, int s) {
#pragma unroll
    for (int t = 0; t < 2; ++t) {
      int c = t * 512 + tid;          // 0..1023 : K chunk (64 rows x 16 chunks)
      int row = c >> 4, sc = (c & 15) ^ (row & 15);
      int cb = t * 512 + (tid & 448);
      async_cp16(Kall + kvbase + (size_t)(kb + row) * HD_ + sc * 8, lK[s] + (size_t)cb * 8);
    }
#pragma unroll
    for (int t = 0; t < 2; ++t) {
      int c = t * 512 + tid;          // 0..1023 : V chunk (128 d-rows x 8 chunks)
      int d = c >> 3, sc = (c & 7) ^ (d & 7);
      int cb = t * 512 + (tid & 448);
      async_cp16(Vt + vtbase + (size_t)d * T_ + kb + sc * 8, lV[s] + (size_t)cb * 8);
    }
  };

  bf16x8 qf[4];
  {
    const bf16_t* qg = Qr + ((((size_t)b * NH_ + h) * Q_) + wq + l15) * HD_ + quad * 8;
#pragma unroll
    for (int kk = 0; kk < 4; ++kk) qf[kk] = *(const bf16x8*)(qg + kk * 32);
  }
  f32x4 ctx[8] = {};
  float Mr[4], Lr[4];
#pragma unroll
  for (int r = 0; r < 4; ++r) { Mr[r] = -3.0e30f; Lr[r] = 0.0f; }
  bf16_t* lPw = lP + wave * 16 * 64;
  const int nt = (PAST_ + qbase + 128) >> 6;
  const int wlimit = PAST_ + wq + 15;

  stageKV(0, 0);  // prologue: tile 0 in flight (4 loads/thread)

  for (int ti = 0; ti < nt; ++ti) {
    const int kb = ti << 6;
    const int cur = ti & 1;
    if (ti + 1 < nt) {
      stageKV(kb + 64, cur ^ 1);
      asm volatile("s_waitcnt vmcnt(4)" ::: "memory");  // tile ti landed; ti+1 in flight
    } else {
      asm volatile("s_waitcnt vmcnt(0)" ::: "memory");
    }
    __builtin_amdgcn_s_barrier();
    asm volatile("" ::: "memory");
    if (kb <= wlimit) {
      const bf16_t* cK = lK[cur];
      const bf16_t* cV = lV[cur];
      f32x4 sacc[4];
#pragma unroll
      for (int nc = 0; nc < 4; ++nc) sacc[nc] = (f32x4){0.f, 0.f, 0.f, 0.f};
      __builtin_amdgcn_s_setprio(1);
#pragma unroll
      for (int nc = 0; nc < 4; ++nc)
#pragma unroll
        for (int kk = 0; kk < 4; ++kk) {
          bf16x8 bk = *(const bf16x8*)(cK + (nc * 16 + l15) * 128 + (((kk * 4 + quad) ^ l15) << 3));
          sacc[nc] = __builtin_amdgcn_mfma_f32_16x16x32_bf16(qf[kk], bk, sacc[nc], 0, 0, 0);
        }
      __builtin_amdgcn_s_setprio(0);
      bool fullvis = (kb + 63 <= PAST_ + wq);
      if (!fullvis) {
#pragma unroll
        for (int nc = 0; nc < 4; ++nc) {
          int tkey = kb + nc * 16 + l15;
#pragma unroll
          for (int r = 0; r < 4; ++r)
            if (tkey > PAST_ + wq + quad * 4 + r) sacc[nc][r] -= 10000.0f;
        }
      }
      // online softmax with defer-max (THR=8)
      float tmax[4];
      bool need = false;
#pragma unroll
      for (int r = 0; r < 4; ++r) {
        float tm = fmaxf(fmaxf(sacc[0][r], sacc[1][r]), fmaxf(sacc[2][r], sacc[3][r]));
#pragma unroll
        for (int mmk = 1; mmk < 16; mmk <<= 1) tm = fmaxf(tm, __shfl_xor(tm, mmk, 64));
        tmax[r] = tm;
        need = need || (tm > Mr[r] + 8.0f);
      }
      if (__any(need)) {
#pragma unroll
        for (int r = 0; r < 4; ++r) {
          float nm = fmaxf(Mr[r], tmax[r]);
          float al = __expf(Mr[r] - nm);
          Mr[r] = nm;
          Lr[r] *= al;
#pragma unroll
          for (int nc2 = 0; nc2 < 8; ++nc2) ctx[nc2][r] *= al;
        }
      }
      float rs[4] = {};
#pragma unroll
      for (int nc = 0; nc < 4; ++nc)
#pragma unroll
        for (int r = 0; r < 4; ++r) {
          float p = __expf(sacc[nc][r] - Mr[r]);
          rs[r] += p;
          int rho = quad * 4 + r;
          int cslot = ((nc * 2 + (l15 >> 3)) ^ (rho & 7));
          lPw[rho * 64 + cslot * 8 + (l15 & 7)] = (bf16_t)p;
        }
#pragma unroll
      for (int r = 0; r < 4; ++r) {
        float s = rs[r];
#pragma unroll
        for (int mmk = 1; mmk < 16; mmk <<= 1) s += __shfl_xor(s, mmk, 64);
        Lr[r] += s;
      }
      asm volatile("s_waitcnt lgkmcnt(0)" ::: "memory");
      __builtin_amdgcn_sched_barrier(0);
      __builtin_amdgcn_s_setprio(1);
#pragma unroll
      for (int kk2 = 0; kk2 < 2; ++kk2) {
        bf16x8 ap = *(const bf16x8*)(lPw + l15 * 64 + (((kk2 * 4 + quad) ^ (l15 & 7)) << 3));
#pragma unroll
        for (int nc2 = 0; nc2 < 8; ++nc2) {
          bf16x8 bv = *(const bf16x8*)(cV + (nc2 * 16 + l15) * 64 + (((kk2 * 4 + quad) ^ (l15 & 7)) << 3));
          ctx[nc2] = __builtin_amdgcn_mfma_f32_16x16x32_bf16(ap, bv, ctx[nc2], 0, 0, 0);
        }
      }
      __builtin_amdgcn_s_setprio(0);
    }
    __builtin_amdgcn_sched_barrier(0);
    __builtin_amdgcn_s_barrier();
  }
  float inv[4];
#pragma unroll
  for (int r = 0; r < 4; ++r) inv[r] = 1.0f / Lr[r];
#pragma unroll
  for (int nc2 = 0; nc2 < 8; ++nc2)
#pragma unroll
    for (int r = 0; r < 4; ++r) {
      size_t row = (size_t)b * Q_ + wq + quad * 4 + r;
      Ctx[row * (NH_ * HD_) + h * HD_ + nc2 * 16 + l15] = (bf16_t)(ctx[nc2][r] * inv[r]);
    }
}

extern "C" void kernel_launch(void* const* d_in, const int* in_sizes, int n_in,
                              void* d_out, int out_size, void* d_ws, size_t ws_size,
                              hipStream_t stream) {
  const float* hidden = (const float*)d_in[0];
  const int* pos = (const int*)d_in[2];
  const float* cosf = (const float*)d_in[3];
  const float* sinf = (const float*)d_in[4];
  const float* past_k = (const float*)d_in[5];
  const float* past_v = (const float*)d_in[6];
  const float* q_w = (const float*)d_in[7];
  const float* k_w = (const float*)d_in[8];
  const float* v_w = (const float*)d_in[9];
  const float* o_w = (const float*)d_in[10];

  float* attn_out = (float*)d_out;
  float* outK = attn_out + (size_t)B_ * Q_ * HID_;
  float* outV = outK + (size_t)B_ * NKV_ * T_ * HD_;

  if (ws_size < 150994944) return;
  char* ws = (char*)d_ws;
  bf16_t* Wqkv = (bf16_t*)(ws);              // 48 MiB
  bf16_t* Xb   = (bf16_t*)(ws + 50331648);   // 16 MiB
  float*  QKV  = (float*)(ws + 67108864);    // 48 MiB
  bf16_t* Qr   = (bf16_t*)(ws + 117440512);  // 16 MiB
  bf16_t* Kall = (bf16_t*)(ws + 134217728);  // 8 MiB
  bf16_t* Vt   = (bf16_t*)(ws + 142606336);  // 8 MiB (d-major transposed V)
  bf16_t* Wo   = (bf16_t*)(ws + 67108864);   // alias QKV (converted after build_vt)
  bf16_t* Ctx  = (bf16_t*)(ws + 50331648);   // alias Xb (written after gemm1)

  cvt_f32_bf16<<<4096, 256, 0, stream>>>(hidden, Xb, 8388608);
  cvt_f32_bf16<<<8192, 256, 0, stream>>>(q_w, Wqkv, 16777216);
  cvt_f32_bf16<<<2048, 256, 0, stream>>>(k_w, Wqkv + 16777216, 4194304);
  cvt_f32_bf16<<<2048, 256, 0, stream>>>(v_w, Wqkv + 20971520, 4194304);
  copy_past<<<2048, 256, 0, stream>>>(past_k, past_v, outK, outV, Kall);
  gemm256<<<dim3(24, 8), 512, 0, stream>>>(Xb, Wqkv, QKV, 2048, 6144, 4096);
  rope_scatter<<<2048, 256, 0, stream>>>(QKV, cosf, sinf, pos, Qr, Kall, outK, outV);
  build_vt<<<dim3(32, 8, 2), 256, 0, stream>>>(past_v, QKV, Vt);
  cvt_f32_bf16<<<8192, 256, 0, stream>>>(o_w, Wo, 16777216);  // after QKV consumed
  attn_fwd<<<512, 512, 0, stream>>>(Qr, Kall, Vt, Ctx);
  gemm128<<<dim3(16, 16), 512, 0, stream>>>(Ctx, Wo, attn_out, 2048, 4096, 4096);
}

// Round 7
// 568.167 us; speedup vs baseline: 1.0993x; 1.0221x over previous
//
#include <hip/hip_runtime.h>
#include <hip/hip_bf16.h>
#include <stdint.h>

typedef __bf16 bf16_t;
typedef bf16_t bf16x8 __attribute__((ext_vector_type(8)));
typedef bf16_t bf16x4 __attribute__((ext_vector_type(4)));
typedef float f32x4 __attribute__((ext_vector_type(4)));

#define B_ 2
#define Q_ 1024
#define PAST_ 1024
#define T_ 2048
#define HID_ 4096
#define NH_ 32
#define NKV_ 8
#define HD_ 128
#define SCALE_ 0.08838834764831845f

__device__ __forceinline__ void async_cp16(const bf16_t* g, bf16_t* l) {
  __builtin_amdgcn_global_load_lds((__attribute__((address_space(1))) void*)g,
                                   (__attribute__((address_space(3))) void*)l, 16, 0, 0);
}

// ---------------- fp32 -> bf16 convert (8 elems/thread) ----------------
__global__ void cvt_f32_bf16(const float* __restrict__ src, bf16_t* __restrict__ dst, size_t n) {
  size_t i = ((size_t)blockIdx.x * blockDim.x + threadIdx.x) * 8;
  if (i >= n) return;
  float4 a = *(const float4*)(src + i);
  float4 b = *(const float4*)(src + i + 4);
  bf16x8 o;
  o[0] = (bf16_t)a.x; o[1] = (bf16_t)a.y; o[2] = (bf16_t)a.z; o[3] = (bf16_t)a.w;
  o[4] = (bf16_t)b.x; o[5] = (bf16_t)b.y; o[6] = (bf16_t)b.z; o[7] = (bf16_t)b.w;
  *(bf16x8*)(dst + i) = o;
}

// ---------------- past KV copy: fp32 -> d_out, bf16 K -> cache ----------------
__global__ void copy_past(const float* __restrict__ pk, const float* __restrict__ pv,
                          float* __restrict__ oK, float* __restrict__ oV,
                          bf16_t* __restrict__ Kall) {
  size_t i = ((size_t)blockIdx.x * 256 + threadIdx.x) * 4;
  if (i >= (size_t)B_ * NKV_ * PAST_ * HD_) return;
  int d = (int)(i & 127);
  size_t r = i >> 7;
  int t = (int)(r & 1023); r >>= 10;
  int g = (int)(r & 7); int b = (int)(r >> 3);
  size_t dst = (((size_t)b * NKV_ + g) * T_ + t) * HD_ + d;
  float4 k4 = *(const float4*)(pk + i);
  float4 v4 = *(const float4*)(pv + i);
  *(float4*)(oK + dst) = k4;
  *(float4*)(oV + dst) = v4;
  bf16x4 kb; kb[0] = (bf16_t)k4.x; kb[1] = (bf16_t)k4.y; kb[2] = (bf16_t)k4.z; kb[3] = (bf16_t)k4.w;
  *(bf16x4*)(Kall + dst) = kb;
}

// ---------------- build transposed V cache: Vt[b][g][d][t] bf16 ----------------
__global__ void build_vt(const float* __restrict__ past_v, const float* __restrict__ QKV,
                         bf16_t* __restrict__ Vt) {
  __shared__ bf16_t tile[64][136];
  const int tid = threadIdx.x;
  const int t0 = blockIdx.x * 64, g = blockIdx.y, b = blockIdx.z;
#pragma unroll
  for (int k = 0; k < 8; ++k) {
    int idx = k * 256 + tid;
    int t = idx >> 5, dc = (idx & 31) * 4;
    int tt = t0 + t;
    const float* src = (tt < PAST_)
        ? past_v + ((((size_t)b * NKV_ + g) * PAST_ + tt) * HD_ + dc)
        : QKV + (((size_t)b * Q_ + (tt - PAST_)) * 6144 + 5120 + g * HD_ + dc);
    float4 v4 = *(const float4*)src;
    tile[t][dc] = (bf16_t)v4.x; tile[t][dc + 1] = (bf16_t)v4.y;
    tile[t][dc + 2] = (bf16_t)v4.z; tile[t][dc + 3] = (bf16_t)v4.w;
  }
  __syncthreads();
#pragma unroll
  for (int k = 0; k < 4; ++k) {
    int idx = k * 256 + tid;
    int d = idx >> 3, c = idx & 7;
    bf16x8 o;
#pragma unroll
    for (int j = 0; j < 8; ++j) o[j] = tile[c * 8 + j][d];
    *(bf16x8*)(Vt + ((((size_t)b * NKV_ + g) * HD_ + d) * T_) + t0 + c * 8) = o;
  }
}

// ---------------- staging helpers (pre-swizzled global src, linear LDS dest) ----
__device__ __forceinline__ void stage_tile(const bf16_t* __restrict__ G, int ldg,
                                           bf16_t* __restrict__ L, int tid) {
#pragma unroll
  for (int t = 0; t < 4; ++t) {
    int c = t * 512 + tid;
    int row = c >> 3, sc = (c & 7) ^ (row & 7);
    int cb = t * 512 + (tid & 448);
    async_cp16(G + (size_t)row * ldg + sc * 8, L + (size_t)cb * 8);
  }
}

__device__ __forceinline__ void stage_tileA128(const bf16_t* __restrict__ G, int ldg,
                                               bf16_t* __restrict__ L, int tid) {
#pragma unroll
  for (int t = 0; t < 2; ++t) {
    int c = t * 512 + tid;
    int row = c >> 3, sc = (c & 7) ^ (row & 7);
    int cb = t * 512 + (tid & 448);
    async_cp16(G + (size_t)row * ldg + sc * 8, L + (size_t)cb * 8);
  }
}

// ---------------- 256x256 8-phase GEMM: C[M,N] = A[M,K] @ W[N,K]^T ----------------
__global__ __launch_bounds__(512, 2)
void gemm256(const bf16_t* __restrict__ A, const bf16_t* __restrict__ W,
             float* __restrict__ C, int M, int N, int K) {
  __shared__ bf16_t sm[2][2][16384];  // [buf][A|B][256*64]
  const int tid = threadIdx.x;
  const int lane = tid & 63;
  const int quad = lane >> 4, l15 = lane & 15;
  const int wave = tid >> 6;
  const int wm = wave >> 2, wn = wave & 3;
  const int bm = blockIdx.y * 256, bn = blockIdx.x * 256;
  const int NT = K >> 6;

  const bf16_t* Ag = A + (size_t)bm * K;
  const bf16_t* Wg = W + (size_t)bn * K;

  f32x4 acc[8][4] = {};

  stage_tile(Ag, K, &sm[0][0][0], tid);
  stage_tile(Wg, K, &sm[0][1][0], tid);
  stage_tile(Ag + 64, K, &sm[1][0][0], tid);
  stage_tile(Wg + 64, K, &sm[1][1][0], tid);
  asm volatile("s_waitcnt vmcnt(8)" ::: "memory");
  __builtin_amdgcn_s_barrier();

  const int arow = wm * 128 + l15;
  const int brow = wn * 64 + l15;
  const int pq = l15 & 7;

  for (int t = 0; t < NT; ++t) {
    const bf16_t* lA = &sm[t & 1][0][0];
    const bf16_t* lB = &sm[t & 1][1][0];
    const int k2 = (t + 2) << 6;
    bf16x8 af[4][2], bf01[2][2], bf23[2][2];

    // ---- P1 ----
#pragma unroll
    for (int m = 0; m < 4; ++m)
#pragma unroll
      for (int kk = 0; kk < 2; ++kk)
        af[m][kk] = *(const bf16x8*)(lA + (arow + m * 16) * 64 + ((((kk << 2) + quad) ^ pq) << 3));
#pragma unroll
    for (int n = 0; n < 2; ++n)
#pragma unroll
      for (int kk = 0; kk < 2; ++kk)
        bf01[n][kk] = *(const bf16x8*)(lB + (brow + n * 16) * 64 + ((((kk << 2) + quad) ^ pq) << 3));
    __builtin_amdgcn_s_barrier();
    asm volatile("s_waitcnt lgkmcnt(0)" ::: "memory");
    __builtin_amdgcn_sched_barrier(0);
    __builtin_amdgcn_s_setprio(1);
#pragma unroll
    for (int m = 0; m < 4; ++m)
#pragma unroll
      for (int n = 0; n < 2; ++n)
#pragma unroll
        for (int kk = 0; kk < 2; ++kk)
          acc[m][n] = __builtin_amdgcn_mfma_f32_16x16x32_bf16(af[m][kk], bf01[n][kk], acc[m][n], 0, 0, 0);
    __builtin_amdgcn_s_setprio(0);
    __builtin_amdgcn_s_barrier();

    // ---- P2 ----
#pragma unroll
    for (int n = 0; n < 2; ++n)
#pragma unroll
      for (int kk = 0; kk < 2; ++kk)
        bf23[n][kk] = *(const bf16x8*)(lB + (brow + (n + 2) * 16) * 64 + ((((kk << 2) + quad) ^ pq) << 3));
    __builtin_amdgcn_s_barrier();
    asm volatile("s_waitcnt lgkmcnt(0)" ::: "memory");
    __builtin_amdgcn_sched_barrier(0);
    __builtin_amdgcn_s_setprio(1);
#pragma unroll
    for (int m = 0; m < 4; ++m)
#pragma unroll
      for (int n = 0; n < 2; ++n)
#pragma unroll
        for (int kk = 0; kk < 2; ++kk)
          acc[m][n + 2] = __builtin_amdgcn_mfma_f32_16x16x32_bf16(af[m][kk], bf23[n][kk], acc[m][n + 2], 0, 0, 0);
    __builtin_amdgcn_s_setprio(0);
    __builtin_amdgcn_s_barrier();

    // ---- P3 ----
#pragma unroll
    for (int m = 0; m < 4; ++m)
#pragma unroll
      for (int kk = 0; kk < 2; ++kk)
        af[m][kk] = *(const bf16x8*)(lA + (arow + (m + 4) * 16) * 64 + ((((kk << 2) + quad) ^ pq) << 3));
    if (t + 2 < NT) stage_tile(Wg + k2, K, &sm[t & 1][1][0], tid);
    __builtin_amdgcn_s_barrier();
    asm volatile("s_waitcnt lgkmcnt(0)" ::: "memory");
    __builtin_amdgcn_sched_barrier(0);
    __builtin_amdgcn_s_setprio(1);
#pragma unroll
    for (int m = 0; m < 4; ++m)
#pragma unroll
      for (int n = 0; n < 2; ++n)
#pragma unroll
        for (int kk = 0; kk < 2; ++kk)
          acc[m + 4][n + 2] = __builtin_amdgcn_mfma_f32_16x16x32_bf16(af[m][kk], bf23[n][kk], acc[m + 4][n + 2], 0, 0, 0);
    __builtin_amdgcn_s_setprio(0);
    __builtin_amdgcn_s_barrier();

    // ---- P4 ----
    if (t + 2 < NT) stage_tile(Ag + k2, K, &sm[t & 1][0][0], tid);
    __builtin_amdgcn_s_barrier();
    __builtin_amdgcn_s_setprio(1);
#pragma unroll
    for (int m = 0; m < 4; ++m)
#pragma unroll
      for (int n = 0; n < 2; ++n)
#pragma unroll
        for (int kk = 0; kk < 2; ++kk)
          acc[m + 4][n] = __builtin_amdgcn_mfma_f32_16x16x32_bf16(af[m][kk], bf01[n][kk], acc[m + 4][n], 0, 0, 0);
    __builtin_amdgcn_s_setprio(0);
    if (t + 2 < NT)
      asm volatile("s_waitcnt vmcnt(8)" ::: "memory");
    else if (t + 2 == NT)
      asm volatile("s_waitcnt vmcnt(0)" ::: "memory");
    __builtin_amdgcn_s_barrier();
  }

#pragma unroll
  for (int m = 0; m < 8; ++m) {
    int row0 = bm + wm * 128 + m * 16 + quad * 4;
#pragma unroll
    for (int n = 0; n < 4; ++n) {
      int col = bn + wn * 64 + n * 16 + l15;
#pragma unroll
      for (int r = 0; r < 4; ++r)
        C[(size_t)(row0 + r) * N + col] = acc[m][n][r];
    }
  }
}

// ---------------- 128x256 4-phase GEMM (full-grid variant for out-proj) ----------
__global__ __launch_bounds__(512, 2)
void gemm128(const bf16_t* __restrict__ A, const bf16_t* __restrict__ W,
             float* __restrict__ C, int M, int N, int K) {
  __shared__ bf16_t smA[2][8192];   // 128 x 64
  __shared__ bf16_t smB[2][16384];  // 256 x 64
  const int tid = threadIdx.x;
  const int lane = tid & 63;
  const int quad = lane >> 4, l15 = lane & 15;
  const int wave = tid >> 6;
  const int wm = wave >> 2, wn = wave & 3;
  const int bm = blockIdx.y * 128, bn = blockIdx.x * 256;
  const int NT = K >> 6;

  const bf16_t* Ag = A + (size_t)bm * K;
  const bf16_t* Wg = W + (size_t)bn * K;

  f32x4 acc[4][4] = {};

  stage_tileA128(Ag, K, &smA[0][0], tid);
  stage_tile(Wg, K, &smB[0][0], tid);
  stage_tileA128(Ag + 64, K, &smA[1][0], tid);
  stage_tile(Wg + 64, K, &smB[1][0], tid);
  asm volatile("s_waitcnt vmcnt(6)" ::: "memory");
  __builtin_amdgcn_s_barrier();

  const int arow = wm * 64 + l15;
  const int brow = wn * 64 + l15;
  const int pq = l15 & 7;

  for (int t = 0; t < NT; ++t) {
    const bf16_t* lA = &smA[t & 1][0];
    const bf16_t* lB = &smB[t & 1][0];
    const int k2 = (t + 2) << 6;
    bf16x8 af[2][2], bf01[2][2], bf23[2][2];

    // ---- P1 ----
#pragma unroll
    for (int m = 0; m < 2; ++m)
#pragma unroll
      for (int kk = 0; kk < 2; ++kk)
        af[m][kk] = *(const bf16x8*)(lA + (arow + m * 16) * 64 + ((((kk << 2) + quad) ^ pq) << 3));
#pragma unroll
    for (int n = 0; n < 2; ++n)
#pragma unroll
      for (int kk = 0; kk < 2; ++kk)
        bf01[n][kk] = *(const bf16x8*)(lB + (brow + n * 16) * 64 + ((((kk << 2) + quad) ^ pq) << 3));
    __builtin_amdgcn_s_barrier();
    asm volatile("s_waitcnt lgkmcnt(0)" ::: "memory");
    __builtin_amdgcn_sched_barrier(0);
    __builtin_amdgcn_s_setprio(1);
#pragma unroll
    for (int m = 0; m < 2; ++m)
#pragma unroll
      for (int n = 0; n < 2; ++n)
#pragma unroll
        for (int kk = 0; kk < 2; ++kk)
          acc[m][n] = __builtin_amdgcn_mfma_f32_16x16x32_bf16(af[m][kk], bf01[n][kk], acc[m][n], 0, 0, 0);
    __builtin_amdgcn_s_setprio(0);
    __builtin_amdgcn_s_barrier();

    // ---- P2 ----
#pragma unroll
    for (int n = 0; n < 2; ++n)
#pragma unroll
      for (int kk = 0; kk < 2; ++kk)
        bf23[n][kk] = *(const bf16x8*)(lB + (brow + (n + 2) * 16) * 64 + ((((kk << 2) + quad) ^ pq) << 3));
    __builtin_amdgcn_s_barrier();
    asm volatile("s_waitcnt lgkmcnt(0)" ::: "memory");
    __builtin_amdgcn_sched_barrier(0);
    __builtin_amdgcn_s_setprio(1);
#pragma unroll
    for (int m = 0; m < 2; ++m)
#pragma unroll
      for (int n = 0; n < 2; ++n)
#pragma unroll
        for (int kk = 0; kk < 2; ++kk)
          acc[m][n + 2] = __builtin_amdgcn_mfma_f32_16x16x32_bf16(af[m][kk], bf23[n][kk], acc[m][n + 2], 0, 0, 0);
    __builtin_amdgcn_s_setprio(0);
    __builtin_amdgcn_s_barrier();

    // ---- P3 ----
#pragma unroll
    for (int m = 0; m < 2; ++m)
#pragma unroll
      for (int kk = 0; kk < 2; ++kk)
        af[m][kk] = *(const bf16x8*)(lA + (arow + (m + 2) * 16) * 64 + ((((kk << 2) + quad) ^ pq) << 3));
    if (t + 2 < NT) stage_tile(Wg + k2, K, &smB[t & 1][0], tid);
    __builtin_amdgcn_s_barrier();
    asm volatile("s_waitcnt lgkmcnt(0)" ::: "memory");
    __builtin_amdgcn_sched_barrier(0);
    __builtin_amdgcn_s_setprio(1);
#pragma unroll
    for (int m = 0; m < 2; ++m)
#pragma unroll
      for (int n = 0; n < 2; ++n)
#pragma unroll
        for (int kk = 0; kk < 2; ++kk)
          acc[m + 2][n + 2] = __builtin_amdgcn_mfma_f32_16x16x32_bf16(af[m][kk], bf23[n][kk], acc[m + 2][n + 2], 0, 0, 0);
    __builtin_amdgcn_s_setprio(0);
    __builtin_amdgcn_s_barrier();

    // ---- P4 ----
    if (t + 2 < NT) stage_tileA128(Ag + k2, K, &smA[t & 1][0], tid);
    __builtin_amdgcn_s_barrier();
    __builtin_amdgcn_s_setprio(1);
#pragma unroll
    for (int m = 0; m < 2; ++m)
#pragma unroll
      for (int n = 0; n < 2; ++n)
#pragma unroll
        for (int kk = 0; kk < 2; ++kk)
          acc[m + 2][n] = __builtin_amdgcn_mfma_f32_16x16x32_bf16(af[m][kk], bf01[n][kk], acc[m + 2][n], 0, 0, 0);
    __builtin_amdgcn_s_setprio(0);
    if (t + 2 < NT)
      asm volatile("s_waitcnt vmcnt(6)" ::: "memory");
    else if (t + 2 == NT)
      asm volatile("s_waitcnt vmcnt(0)" ::: "memory");
    __builtin_amdgcn_s_barrier();
  }

#pragma unroll
  for (int m = 0; m < 4; ++m) {
    int row0 = bm + wm * 64 + m * 16 + quad * 4;
#pragma unroll
    for (int n = 0; n < 4; ++n) {
      int col = bn + wn * 64 + n * 16 + l15;
#pragma unroll
      for (int r = 0; r < 4; ++r)
        C[(size_t)(row0 + r) * N + col] = acc[m][n][r];
    }
  }
}

// ---------------- RoPE + scatter (Q pre-scaled by SCALE for attn) ----------------
__global__ void rope_scatter(const float* __restrict__ QKV, const float* __restrict__ cosf,
                             const float* __restrict__ sinf, const int* __restrict__ pos_ids,
                             bf16_t* __restrict__ Qr, bf16_t* __restrict__ Kall,
                             float* __restrict__ outK, float* __restrict__ outV) {
  int m = blockIdx.x;
  int b = m >> 10, s = m & 1023;
  int pos = pos_ids[(size_t)b * Q_ + s];
  const float* row = QKV + (size_t)m * 6144;
  int tid = threadIdx.x;
  for (int p = tid; p < NH_ * 64; p += 256) {
    int h = p >> 6, d = p & 63;
    float x1 = row[h * 128 + d], x2 = row[h * 128 + d + 64];
    float c = cosf[pos * 64 + d], sn = sinf[pos * 64 + d];
    size_t qb = (((size_t)b * NH_ + h) * Q_ + s) * HD_;
    Qr[qb + d] = (bf16_t)((x1 * c - x2 * sn) * SCALE_);
    Qr[qb + d + 64] = (bf16_t)((x2 * c + x1 * sn) * SCALE_);
  }
  for (int p = tid; p < NKV_ * 64; p += 256) {
    int g = p >> 6, d = p & 63;
    float x1 = row[4096 + g * 128 + d], x2 = row[4096 + g * 128 + d + 64];
    float c = cosf[pos * 64 + d], sn = sinf[pos * 64 + d];
    float o1 = x1 * c - x2 * sn, o2 = x2 * c + x1 * sn;
    size_t kbi = (((size_t)b * NKV_ + g) * T_ + PAST_ + s) * HD_;
    Kall[kbi + d] = (bf16_t)o1; Kall[kbi + d + 64] = (bf16_t)o2;
    outK[kbi + d] = o1; outK[kbi + d + 64] = o2;
  }
  for (int e = tid; e < NKV_ * HD_; e += 256) {
    int g = e >> 7, d = e & 127;
    float v = row[5120 + g * 128 + d];
    outV[(((size_t)b * NKV_ + g) * T_ + PAST_ + s) * HD_ + d] = v;
  }
}

// ---------------- flash attention (8 waves x 32 q-rows, QBLK=256) ----------------
// LDS-throughput-bound fix: each wave owns TWO 16-row groups sharing the same
// K/V fragment reads (K+V LDS traffic per q-row halves), and the softmax row-SUM
// is computed by an extra MFMA against a ones-vector (replaces 32 ds_bpermute
// chains with 4 MFMAs). Grid 256 = 1 block/CU. LDS 96 KiB: lK dbuf 32K +
// lV dbuf 32K + lP 32K. Pipeline: dbuf + counted vmcnt(4), raw s_barrier.
__global__ __launch_bounds__(512, 2)
void attn_fwd(const bf16_t* __restrict__ Qr, const bf16_t* __restrict__ Kall,
              const bf16_t* __restrict__ Vt, bf16_t* __restrict__ Ctx) {
  __shared__ bf16_t lK[2][64 * 128];
  __shared__ bf16_t lV[2][128 * 64];
  __shared__ bf16_t lP[8 * 2 * 16 * 64];
  const int tid = threadIdx.x;
  const int wave = tid >> 6, lane = tid & 63;
  const int quad = lane >> 4, l15 = lane & 15;
  const int i = blockIdx.x;
  const int xcd = i & 7;
  const int j = i >> 3;
  const int pairsel = j & 1;
  const int idx = j >> 1;          // 0..15
  const int h_in = idx & 3;
  const int qt = 3 - (idx >> 2);   // heavy first (4 q-tiles of 256 rows)
  const int b = pairsel, kv = xcd;
  const int h = kv * 4 + h_in;
  const int qbase = qt * 256;
  const int wq = qbase + wave * 32;       // group0 rows wq..wq+15, group1 wq+16..wq+31
  const size_t kvbase = ((size_t)b * NKV_ + kv) * T_ * HD_;
  const size_t vtbase = ((size_t)b * NKV_ + kv) * HD_ * T_;

  auto stageKV = [&](int kb, int s) {
#pragma unroll
    for (int t = 0; t < 2; ++t) {
      int c = t * 512 + tid;
      int row = c >> 4, sc = (c & 15) ^ (row & 15);
      int cb = t * 512 + (tid & 448);
      async_cp16(Kall + kvbase + (size_t)(kb + row) * HD_ + sc * 8, lK[s] + (size_t)cb * 8);
    }
#pragma unroll
    for (int t = 0; t < 2; ++t) {
      int c = t * 512 + tid;
      int d = c >> 3, sc = (c & 7) ^ (d & 7);
      int cb = t * 512 + (tid & 448);
      async_cp16(Vt + vtbase + (size_t)d * T_ + kb + sc * 8, lV[s] + (size_t)cb * 8);
    }
  };

  bf16x8 qf[2][4];
#pragma unroll
  for (int g = 0; g < 2; ++g) {
    const bf16_t* qg = Qr + ((((size_t)b * NH_ + h) * Q_) + wq + g * 16 + l15) * HD_ + quad * 8;
#pragma unroll
    for (int kk = 0; kk < 4; ++kk) qf[g][kk] = *(const bf16x8*)(qg + kk * 32);
  }
  bf16x8 ones;
#pragma unroll
  for (int e = 0; e < 8; ++e) ones[e] = (bf16_t)1.0f;

  f32x4 ctx[2][8] = {};
  float Mr[2][4], Lr[2][4];
#pragma unroll
  for (int g = 0; g < 2; ++g)
#pragma unroll
    for (int r = 0; r < 4; ++r) { Mr[g][r] = -3.0e30f; Lr[g][r] = 0.0f; }
  bf16_t* lPw0 = lP + wave * 2048;
  bf16_t* lPw1 = lPw0 + 1024;
  const int nt = (PAST_ + qbase + 256) >> 6;

  stageKV(0, 0);  // prologue: tile 0 in flight (4 loads/thread)

  for (int ti = 0; ti < nt; ++ti) {
    const int kb = ti << 6;
    const int cur = ti & 1;
    if (ti + 1 < nt) {
      stageKV(kb + 64, cur ^ 1);
      asm volatile("s_waitcnt vmcnt(4)" ::: "memory");
    } else {
      asm volatile("s_waitcnt vmcnt(0)" ::: "memory");
    }
    __builtin_amdgcn_s_barrier();
    asm volatile("" ::: "memory");
    if (kb <= PAST_ + wq + 31) {
      const bf16_t* cK = lK[cur];
      const bf16_t* cV = lV[cur];
      f32x4 sacc[2][4];
#pragma unroll
      for (int g = 0; g < 2; ++g)
#pragma unroll
        for (int nc = 0; nc < 4; ++nc) sacc[g][nc] = (f32x4){0.f, 0.f, 0.f, 0.f};
      // QK^T for both row groups sharing the K-fragment reads
      __builtin_amdgcn_s_setprio(1);
#pragma unroll
      for (int nc = 0; nc < 4; ++nc) {
        bf16x8 bk[4];
#pragma unroll
        for (int kk = 0; kk < 4; ++kk)
          bk[kk] = *(const bf16x8*)(cK + (nc * 16 + l15) * 128 + (((kk * 4 + quad) ^ l15) << 3));
#pragma unroll
        for (int kk = 0; kk < 4; ++kk)
          sacc[0][nc] = __builtin_amdgcn_mfma_f32_16x16x32_bf16(qf[0][kk], bk[kk], sacc[0][nc], 0, 0, 0);
#pragma unroll
        for (int kk = 0; kk < 4; ++kk)
          sacc[1][nc] = __builtin_amdgcn_mfma_f32_16x16x32_bf16(qf[1][kk], bk[kk], sacc[1][nc], 0, 0, 0);
      }
      __builtin_amdgcn_s_setprio(0);
      // mask + softmax per group
      bool need = false;
      float tmax[2][4];
#pragma unroll
      for (int g = 0; g < 2; ++g) {
        int wqg = wq + g * 16;
        bool fullvis = (kb + 63 <= PAST_ + wqg);
        if (!fullvis) {
#pragma unroll
          for (int nc = 0; nc < 4; ++nc) {
            int tkey = kb + nc * 16 + l15;
#pragma unroll
            for (int r = 0; r < 4; ++r)
              if (tkey > PAST_ + wqg + quad * 4 + r) sacc[g][nc][r] -= 10000.0f;
          }
        }
#pragma unroll
        for (int r = 0; r < 4; ++r) {
          float tm = fmaxf(fmaxf(sacc[g][0][r], sacc[g][1][r]), fmaxf(sacc[g][2][r], sacc[g][3][r]));
#pragma unroll
          for (int mmk = 1; mmk < 16; mmk <<= 1) tm = fmaxf(tm, __shfl_xor(tm, mmk, 64));
          tmax[g][r] = tm;
          need = need || (tm > Mr[g][r] + 8.0f);
        }
      }
      if (__any(need)) {
#pragma unroll
        for (int g = 0; g < 2; ++g)
#pragma unroll
          for (int r = 0; r < 4; ++r) {
            float nm = fmaxf(Mr[g][r], tmax[g][r]);
            float al = __expf(Mr[g][r] - nm);
            Mr[g][r] = nm;
            Lr[g][r] *= al;
#pragma unroll
            for (int nc2 = 0; nc2 < 8; ++nc2) ctx[g][nc2][r] *= al;
          }
      }
      // P = exp(S - M), store to per-group LDS slices
#pragma unroll
      for (int g = 0; g < 2; ++g) {
        bf16_t* lPw = g ? lPw1 : lPw0;
#pragma unroll
        for (int nc = 0; nc < 4; ++nc)
#pragma unroll
          for (int r = 0; r < 4; ++r) {
            float p = __expf(sacc[g][nc][r] - Mr[g][r]);
            int rho = quad * 4 + r;
            int cslot = ((nc * 2 + (l15 >> 3)) ^ (rho & 7));
            lPw[rho * 64 + cslot * 8 + (l15 & 7)] = (bf16_t)p;
          }
      }
      asm volatile("s_waitcnt lgkmcnt(0)" ::: "memory");
      __builtin_amdgcn_sched_barrier(0);
      // PV + row-sum (ones-MFMA) sharing the V-fragment reads
      bf16x8 ap0[2], ap1[2];
#pragma unroll
      for (int kk2 = 0; kk2 < 2; ++kk2) {
        int off = (((kk2 * 4 + quad) ^ (l15 & 7)) << 3);
        ap0[kk2] = *(const bf16x8*)(lPw0 + l15 * 64 + off);
        ap1[kk2] = *(const bf16x8*)(lPw1 + l15 * 64 + off);
      }
      __builtin_amdgcn_s_setprio(1);
      f32x4 ls0 = (f32x4){0.f, 0.f, 0.f, 0.f}, ls1 = (f32x4){0.f, 0.f, 0.f, 0.f};
#pragma unroll
      for (int kk2 = 0; kk2 < 2; ++kk2) {
        ls0 = __builtin_amdgcn_mfma_f32_16x16x32_bf16(ap0[kk2], ones, ls0, 0, 0, 0);
        ls1 = __builtin_amdgcn_mfma_f32_16x16x32_bf16(ap1[kk2], ones, ls1, 0, 0, 0);
      }
#pragma unroll
      for (int nc2 = 0; nc2 < 8; ++nc2)
#pragma unroll
        for (int kk2 = 0; kk2 < 2; ++kk2) {
          bf16x8 bv = *(const bf16x8*)(cV + (nc2 * 16 + l15) * 64 + (((kk2 * 4 + quad) ^ (l15 & 7)) << 3));
          ctx[0][nc2] = __builtin_amdgcn_mfma_f32_16x16x32_bf16(ap0[kk2], bv, ctx[0][nc2], 0, 0, 0);
          ctx[1][nc2] = __builtin_amdgcn_mfma_f32_16x16x32_bf16(ap1[kk2], bv, ctx[1][nc2], 0, 0, 0);
        }
      __builtin_amdgcn_s_setprio(0);
#pragma unroll
      for (int r = 0; r < 4; ++r) { Lr[0][r] += ls0[r]; Lr[1][r] += ls1[r]; }
    }
    __builtin_amdgcn_sched_barrier(0);
    __builtin_amdgcn_s_barrier();
  }
#pragma unroll
  for (int g = 0; g < 2; ++g) {
    float inv[4];
#pragma unroll
    for (int r = 0; r < 4; ++r) inv[r] = 1.0f / Lr[g][r];
#pragma unroll
    for (int nc2 = 0; nc2 < 8; ++nc2)
#pragma unroll
      for (int r = 0; r < 4; ++r) {
        size_t row = (size_t)b * Q_ + wq + g * 16 + quad * 4 + r;
        Ctx[row * (NH_ * HD_) + h * HD_ + nc2 * 16 + l15] = (bf16_t)(ctx[g][nc2][r] * inv[r]);
      }
  }
}

extern "C" void kernel_launch(void* const* d_in, const int* in_sizes, int n_in,
                              void* d_out, int out_size, void* d_ws, size_t ws_size,
                              hipStream_t stream) {
  const float* hidden = (const float*)d_in[0];
  const int* pos = (const int*)d_in[2];
  const float* cosf = (const float*)d_in[3];
  const float* sinf = (const float*)d_in[4];
  const float* past_k = (const float*)d_in[5];
  const float* past_v = (const float*)d_in[6];
  const float* q_w = (const float*)d_in[7];
  const float* k_w = (const float*)d_in[8];
  const float* v_w = (const float*)d_in[9];
  const float* o_w = (const float*)d_in[10];

  float* attn_out = (float*)d_out;
  float* outK = attn_out + (size_t)B_ * Q_ * HID_;
  float* outV = outK + (size_t)B_ * NKV_ * T_ * HD_;

  if (ws_size < 150994944) return;
  char* ws = (char*)d_ws;
  bf16_t* Wqkv = (bf16_t*)(ws);              // 48 MiB
  bf16_t* Xb   = (bf16_t*)(ws + 50331648);   // 16 MiB
  float*  QKV  = (float*)(ws + 67108864);    // 48 MiB
  bf16_t* Qr   = (bf16_t*)(ws + 117440512);  // 16 MiB
  bf16_t* Kall = (bf16_t*)(ws + 134217728);  // 8 MiB
  bf16_t* Vt   = (bf16_t*)(ws + 142606336);  // 8 MiB (d-major transposed V)
  bf16_t* Wo   = (bf16_t*)(ws + 67108864);   // alias QKV (converted after build_vt)
  bf16_t* Ctx  = (bf16_t*)(ws + 50331648);   // alias Xb (written after gemm1)

  cvt_f32_bf16<<<4096, 256, 0, stream>>>(hidden, Xb, 8388608);
  cvt_f32_bf16<<<8192, 256, 0, stream>>>(q_w, Wqkv, 16777216);
  cvt_f32_bf16<<<2048, 256, 0, stream>>>(k_w, Wqkv + 16777216, 4194304);
  cvt_f32_bf16<<<2048, 256, 0, stream>>>(v_w, Wqkv + 20971520, 4194304);
  copy_past<<<2048, 256, 0, stream>>>(past_k, past_v, outK, outV, Kall);
  gemm256<<<dim3(24, 8), 512, 0, stream>>>(Xb, Wqkv, QKV, 2048, 6144, 4096);
  rope_scatter<<<2048, 256, 0, stream>>>(QKV, cosf, sinf, pos, Qr, Kall, outK, outV);
  build_vt<<<dim3(32, 8, 2), 256, 0, stream>>>(past_v, QKV, Vt);
  cvt_f32_bf16<<<8192, 256, 0, stream>>>(o_w, Wo, 16777216);  // after QKV consumed
  attn_fwd<<<256, 512, 0, stream>>>(Qr, Kall, Vt, Ctx);
  gemm128<<<dim3(16, 16), 512, 0, stream>>>(Ctx, Wo, attn_out, 2048, 4096, 4096);
}

// Round 8
// 551.741 us; speedup vs baseline: 1.1320x; 1.0298x over previous
//
#include <hip/hip_runtime.h>
#include <hip/hip_bf16.h>
#include <stdint.h>

typedef __bf16 bf16_t;
typedef bf16_t bf16x8 __attribute__((ext_vector_type(8)));
typedef bf16_t bf16x4 __attribute__((ext_vector_type(4)));
typedef float f32x4 __attribute__((ext_vector_type(4)));

#define B_ 2
#define Q_ 1024
#define PAST_ 1024
#define T_ 2048
#define HID_ 4096
#define NH_ 32
#define NKV_ 8
#define HD_ 128
#define SCALE_ 0.08838834764831845f

__device__ __forceinline__ void async_cp16(const bf16_t* g, bf16_t* l) {
  __builtin_amdgcn_global_load_lds((__attribute__((address_space(1))) void*)g,
                                   (__attribute__((address_space(3))) void*)l, 16, 0, 0);
}

// ---------------- fp32 -> bf16 convert (8 elems/thread) ----------------
__global__ void cvt_f32_bf16(const float* __restrict__ src, bf16_t* __restrict__ dst, size_t n) {
  size_t i = ((size_t)blockIdx.x * blockDim.x + threadIdx.x) * 8;
  if (i >= n) return;
  float4 a = *(const float4*)(src + i);
  float4 b = *(const float4*)(src + i + 4);
  bf16x8 o;
  o[0] = (bf16_t)a.x; o[1] = (bf16_t)a.y; o[2] = (bf16_t)a.z; o[3] = (bf16_t)a.w;
  o[4] = (bf16_t)b.x; o[5] = (bf16_t)b.y; o[6] = (bf16_t)b.z; o[7] = (bf16_t)b.w;
  *(bf16x8*)(dst + i) = o;
}

// ---------------- past KV copy + V-transpose fused ----------------
// grid (16, 8, 2) x 256 thr: block = (t0, g, b), 64 t x 128 d tile.
// Streams past K/V -> fp32 outs + bf16 K cache, and writes transposed V
// (Vt[b][g][d][t]) via LDS tile — kills build_vt's 64MB re-read of past_v.
__global__ void copy_past(const float* __restrict__ pk, const float* __restrict__ pv,
                          float* __restrict__ oK, float* __restrict__ oV,
                          bf16_t* __restrict__ Kall, bf16_t* __restrict__ Vt) {
  __shared__ bf16_t tile[64][136];
  const int tid = threadIdx.x;
  const int t0 = blockIdx.x * 64, g = blockIdx.y, b = blockIdx.z;
  const size_t srcbase = (((size_t)b * NKV_ + g) * PAST_ + t0) * HD_;
  const size_t dstbase = (((size_t)b * NKV_ + g) * T_ + t0) * HD_;
#pragma unroll
  for (int k = 0; k < 8; ++k) {
    int idx = k * 256 + tid;
    int t = idx >> 5, dc = (idx & 31) * 4;
    size_t so = srcbase + (size_t)t * HD_ + dc;
    size_t dofs = dstbase + (size_t)t * HD_ + dc;
    float4 k4 = *(const float4*)(pk + so);
    float4 v4 = *(const float4*)(pv + so);
    *(float4*)(oK + dofs) = k4;
    *(float4*)(oV + dofs) = v4;
    bf16x4 kb; kb[0] = (bf16_t)k4.x; kb[1] = (bf16_t)k4.y; kb[2] = (bf16_t)k4.z; kb[3] = (bf16_t)k4.w;
    *(bf16x4*)(Kall + dofs) = kb;
    tile[t][dc] = (bf16_t)v4.x; tile[t][dc + 1] = (bf16_t)v4.y;
    tile[t][dc + 2] = (bf16_t)v4.z; tile[t][dc + 3] = (bf16_t)v4.w;
  }
  __syncthreads();
#pragma unroll
  for (int k = 0; k < 4; ++k) {
    int idx = k * 256 + tid;
    int d = idx >> 3, c = idx & 7;
    bf16x8 o;
#pragma unroll
    for (int j = 0; j < 8; ++j) o[j] = tile[c * 8 + j][d];
    *(bf16x8*)(Vt + ((((size_t)b * NKV_ + g) * HD_ + d) * T_) + t0 + c * 8) = o;
  }
}

// ---------------- build transposed V cache for NEW tokens only ----------------
// grid (16, 8, 2): t0 in [PAST, T). Source: QKV V-section.
__global__ void build_vt(const float* __restrict__ QKV, bf16_t* __restrict__ Vt) {
  __shared__ bf16_t tile[64][136];
  const int tid = threadIdx.x;
  const int t0 = PAST_ + blockIdx.x * 64, g = blockIdx.y, b = blockIdx.z;
#pragma unroll
  for (int k = 0; k < 8; ++k) {
    int idx = k * 256 + tid;
    int t = idx >> 5, dc = (idx & 31) * 4;
    int s = t0 - PAST_ + t;
    const float* src = QKV + (((size_t)b * Q_ + s) * 6144 + 5120 + g * HD_ + dc);
    float4 v4 = *(const float4*)src;
    tile[t][dc] = (bf16_t)v4.x; tile[t][dc + 1] = (bf16_t)v4.y;
    tile[t][dc + 2] = (bf16_t)v4.z; tile[t][dc + 3] = (bf16_t)v4.w;
  }
  __syncthreads();
#pragma unroll
  for (int k = 0; k < 4; ++k) {
    int idx = k * 256 + tid;
    int d = idx >> 3, c = idx & 7;
    bf16x8 o;
#pragma unroll
    for (int j = 0; j < 8; ++j) o[j] = tile[c * 8 + j][d];
    *(bf16x8*)(Vt + ((((size_t)b * NKV_ + g) * HD_ + d) * T_) + t0 + c * 8) = o;
  }
}

// ---------------- staging helpers (pre-swizzled global src, linear LDS dest) ----
__device__ __forceinline__ void stage_tile256(const bf16_t* __restrict__ G, int ldg,
                                              bf16_t* __restrict__ L, int tid) {
#pragma unroll
  for (int t = 0; t < 4; ++t) {
    int c = t * 512 + tid;
    int row = c >> 3, sc = (c & 7) ^ (row & 7);
    int cb = t * 512 + (tid & 448);
    async_cp16(G + (size_t)row * ldg + sc * 8, L + (size_t)cb * 8);
  }
}

__device__ __forceinline__ void stage_tile192(const bf16_t* __restrict__ G, int ldg,
                                              bf16_t* __restrict__ L, int tid) {
#pragma unroll
  for (int t = 0; t < 3; ++t) {
    int c = t * 512 + tid;
    int row = c >> 3, sc = (c & 7) ^ (row & 7);
    int cb = t * 512 + (tid & 448);
    async_cp16(G + (size_t)row * ldg + sc * 8, L + (size_t)cb * 8);
  }
}

__device__ __forceinline__ void stage_tile128(const bf16_t* __restrict__ G, int ldg,
                                              bf16_t* __restrict__ L, int tid) {
#pragma unroll
  for (int t = 0; t < 2; ++t) {
    int c = t * 512 + tid;
    int row = c >> 3, sc = (c & 7) ^ (row & 7);
    int cb = t * 512 + (tid & 448);
    async_cp16(G + (size_t)row * ldg + sc * 8, L + (size_t)cb * 8);
  }
}

// ---------------- 256x192 4-phase GEMM (QKV: grid 32x8 = 256 blocks = 1/CU) ------
// 8 waves (2M x 4N), per-wave 128x48 out, BK=64, dbuf LDS 112 KiB.
// Ledger: 7 loads/tile (B=3 in P3, A=4 in P4); steady vmcnt(7), never 0 in loop.
__global__ __launch_bounds__(512, 2)
void gemm192(const bf16_t* __restrict__ A, const bf16_t* __restrict__ W,
             float* __restrict__ C, int M, int N, int K) {
  __shared__ bf16_t smA[2][16384];  // 256 x 64
  __shared__ bf16_t smB[2][12288];  // 192 x 64
  const int tid = threadIdx.x;
  const int lane = tid & 63;
  const int quad = lane >> 4, l15 = lane & 15;
  const int wave = tid >> 6;
  const int wm = wave >> 2, wn = wave & 3;
  const int bm = blockIdx.y * 256, bn = blockIdx.x * 192;
  const int NT = K >> 6;

  const bf16_t* Ag = A + (size_t)bm * K;
  const bf16_t* Wg = W + (size_t)bn * K;

  f32x4 acc[8][3] = {};

  stage_tile256(Ag, K, &smA[0][0], tid);
  stage_tile192(Wg, K, &smB[0][0], tid);
  stage_tile256(Ag + 64, K, &smA[1][0], tid);
  stage_tile192(Wg + 64, K, &smB[1][0], tid);
  asm volatile("s_waitcnt vmcnt(7)" ::: "memory");
  __builtin_amdgcn_s_barrier();

  const int arow = wm * 128 + l15;
  const int brow = wn * 48 + l15;
  const int pq = l15 & 7;

  for (int t = 0; t < NT; ++t) {
    const bf16_t* lA = &smA[t & 1][0];
    const bf16_t* lB = &smB[t & 1][0];
    const int k2 = (t + 2) << 6;
    bf16x8 af[4][2], bf01[2][2], bf2[2];

    // ---- P1: read A[m0-3], B[n0-1]; compute acc[0..3][0..1] ----
#pragma unroll
    for (int m = 0; m < 4; ++m)
#pragma unroll
      for (int kk = 0; kk < 2; ++kk)
        af[m][kk] = *(const bf16x8*)(lA + (arow + m * 16) * 64 + ((((kk << 2) + quad) ^ pq) << 3));
#pragma unroll
    for (int n = 0; n < 2; ++n)
#pragma unroll
      for (int kk = 0; kk < 2; ++kk)
        bf01[n][kk] = *(const bf16x8*)(lB + (brow + n * 16) * 64 + ((((kk << 2) + quad) ^ pq) << 3));
    __builtin_amdgcn_s_barrier();
    asm volatile("s_waitcnt lgkmcnt(0)" ::: "memory");
    __builtin_amdgcn_sched_barrier(0);
    __builtin_amdgcn_s_setprio(1);
#pragma unroll
    for (int m = 0; m < 4; ++m)
#pragma unroll
      for (int n = 0; n < 2; ++n)
#pragma unroll
        for (int kk = 0; kk < 2; ++kk)
          acc[m][n] = __builtin_amdgcn_mfma_f32_16x16x32_bf16(af[m][kk], bf01[n][kk], acc[m][n], 0, 0, 0);
    __builtin_amdgcn_s_setprio(0);
    __builtin_amdgcn_s_barrier();

    // ---- P2: read B[n2]; compute acc[0..3][2] ----
#pragma unroll
    for (int kk = 0; kk < 2; ++kk)
      bf2[kk] = *(const bf16x8*)(lB + (brow + 32) * 64 + ((((kk << 2) + quad) ^ pq) << 3));
    __builtin_amdgcn_s_barrier();
    asm volatile("s_waitcnt lgkmcnt(0)" ::: "memory");
    __builtin_amdgcn_sched_barrier(0);
    __builtin_amdgcn_s_setprio(1);
#pragma unroll
    for (int m = 0; m < 4; ++m)
#pragma unroll
      for (int kk = 0; kk < 2; ++kk)
        acc[m][2] = __builtin_amdgcn_mfma_f32_16x16x32_bf16(af[m][kk], bf2[kk], acc[m][2], 0, 0, 0);
    __builtin_amdgcn_s_setprio(0);
    __builtin_amdgcn_s_barrier();

    // ---- P3: read A[m4-7]; stage B(t+2); compute acc[4..7][2] ----
#pragma unroll
    for (int m = 0; m < 4; ++m)
#pragma unroll
      for (int kk = 0; kk < 2; ++kk)
        af[m][kk] = *(const bf16x8*)(lA + (arow + (m + 4) * 16) * 64 + ((((kk << 2) + quad) ^ pq) << 3));
    if (t + 2 < NT) stage_tile192(Wg + k2, K, &smB[t & 1][0], tid);
    __builtin_amdgcn_s_barrier();
    asm volatile("s_waitcnt lgkmcnt(0)" ::: "memory");
    __builtin_amdgcn_sched_barrier(0);
    __builtin_amdgcn_s_setprio(1);
#pragma unroll
    for (int m = 0; m < 4; ++m)
#pragma unroll
      for (int kk = 0; kk < 2; ++kk)
        acc[m + 4][2] = __builtin_amdgcn_mfma_f32_16x16x32_bf16(af[m][kk], bf2[kk], acc[m + 4][2], 0, 0, 0);
    __builtin_amdgcn_s_setprio(0);
    __builtin_amdgcn_s_barrier();

    // ---- P4: stage A(t+2); compute acc[4..7][0..1]; counted drain ----
    if (t + 2 < NT) stage_tile256(Ag + k2, K, &smA[t & 1][0], tid);
    __builtin_amdgcn_s_barrier();
    __builtin_amdgcn_s_setprio(1);
#pragma unroll
    for (int m = 0; m < 4; ++m)
#pragma unroll
      for (int n = 0; n < 2; ++n)
#pragma unroll
        for (int kk = 0; kk < 2; ++kk)
          acc[m + 4][n] = __builtin_amdgcn_mfma_f32_16x16x32_bf16(af[m][kk], bf01[n][kk], acc[m + 4][n], 0, 0, 0);
    __builtin_amdgcn_s_setprio(0);
    if (t + 2 < NT)
      asm volatile("s_waitcnt vmcnt(7)" ::: "memory");
    else if (t + 2 == NT)
      asm volatile("s_waitcnt vmcnt(0)" ::: "memory");
    __builtin_amdgcn_s_barrier();
  }

#pragma unroll
  for (int m = 0; m < 8; ++m) {
    int row0 = bm + wm * 128 + m * 16 + quad * 4;
#pragma unroll
    for (int n = 0; n < 3; ++n) {
      int col = bn + wn * 48 + n * 16 + l15;
#pragma unroll
      for (int r = 0; r < 4; ++r)
        C[(size_t)(row0 + r) * N + col] = acc[m][n][r];
    }
  }
}

// ---------------- 128x256 4-phase GEMM (out-proj: grid 16x16 = 256 blocks) -------
__global__ __launch_bounds__(512, 2)
void gemm128(const bf16_t* __restrict__ A, const bf16_t* __restrict__ W,
             float* __restrict__ C, int M, int N, int K) {
  __shared__ bf16_t smA[2][8192];   // 128 x 64
  __shared__ bf16_t smB[2][16384];  // 256 x 64
  const int tid = threadIdx.x;
  const int lane = tid & 63;
  const int quad = lane >> 4, l15 = lane & 15;
  const int wave = tid >> 6;
  const int wm = wave >> 2, wn = wave & 3;
  const int bm = blockIdx.y * 128, bn = blockIdx.x * 256;
  const int NT = K >> 6;

  const bf16_t* Ag = A + (size_t)bm * K;
  const bf16_t* Wg = W + (size_t)bn * K;

  f32x4 acc[4][4] = {};

  stage_tile128(Ag, K, &smA[0][0], tid);
  stage_tile256(Wg, K, &smB[0][0], tid);
  stage_tile128(Ag + 64, K, &smA[1][0], tid);
  stage_tile256(Wg + 64, K, &smB[1][0], tid);
  asm volatile("s_waitcnt vmcnt(6)" ::: "memory");
  __builtin_amdgcn_s_barrier();

  const int arow = wm * 64 + l15;
  const int brow = wn * 64 + l15;
  const int pq = l15 & 7;

  for (int t = 0; t < NT; ++t) {
    const bf16_t* lA = &smA[t & 1][0];
    const bf16_t* lB = &smB[t & 1][0];
    const int k2 = (t + 2) << 6;
    bf16x8 af[2][2], bf01[2][2], bf23[2][2];

    // ---- P1 ----
#pragma unroll
    for (int m = 0; m < 2; ++m)
#pragma unroll
      for (int kk = 0; kk < 2; ++kk)
        af[m][kk] = *(const bf16x8*)(lA + (arow + m * 16) * 64 + ((((kk << 2) + quad) ^ pq) << 3));
#pragma unroll
    for (int n = 0; n < 2; ++n)
#pragma unroll
      for (int kk = 0; kk < 2; ++kk)
        bf01[n][kk] = *(const bf16x8*)(lB + (brow + n * 16) * 64 + ((((kk << 2) + quad) ^ pq) << 3));
    __builtin_amdgcn_s_barrier();
    asm volatile("s_waitcnt lgkmcnt(0)" ::: "memory");
    __builtin_amdgcn_sched_barrier(0);
    __builtin_amdgcn_s_setprio(1);
#pragma unroll
    for (int m = 0; m < 2; ++m)
#pragma unroll
      for (int n = 0; n < 2; ++n)
#pragma unroll
        for (int kk = 0; kk < 2; ++kk)
          acc[m][n] = __builtin_amdgcn_mfma_f32_16x16x32_bf16(af[m][kk], bf01[n][kk], acc[m][n], 0, 0, 0);
    __builtin_amdgcn_s_setprio(0);
    __builtin_amdgcn_s_barrier();

    // ---- P2 ----
#pragma unroll
    for (int n = 0; n < 2; ++n)
#pragma unroll
      for (int kk = 0; kk < 2; ++kk)
        bf23[n][kk] = *(const bf16x8*)(lB + (brow + (n + 2) * 16) * 64 + ((((kk << 2) + quad) ^ pq) << 3));
    __builtin_amdgcn_s_barrier();
    asm volatile("s_waitcnt lgkmcnt(0)" ::: "memory");
    __builtin_amdgcn_sched_barrier(0);
    __builtin_amdgcn_s_setprio(1);
#pragma unroll
    for (int m = 0; m < 2; ++m)
#pragma unroll
      for (int n = 0; n < 2; ++n)
#pragma unroll
        for (int kk = 0; kk < 2; ++kk)
          acc[m][n + 2] = __builtin_amdgcn_mfma_f32_16x16x32_bf16(af[m][kk], bf23[n][kk], acc[m][n + 2], 0, 0, 0);
    __builtin_amdgcn_s_setprio(0);
    __builtin_amdgcn_s_barrier();

    // ---- P3 ----
#pragma unroll
    for (int m = 0; m < 2; ++m)
#pragma unroll
      for (int kk = 0; kk < 2; ++kk)
        af[m][kk] = *(const bf16x8*)(lA + (arow + (m + 2) * 16) * 64 + ((((kk << 2) + quad) ^ pq) << 3));
    if (t + 2 < NT) stage_tile256(Wg + k2, K, &smB[t & 1][0], tid);
    __builtin_amdgcn_s_barrier();
    asm volatile("s_waitcnt lgkmcnt(0)" ::: "memory");
    __builtin_amdgcn_sched_barrier(0);
    __builtin_amdgcn_s_setprio(1);
#pragma unroll
    for (int m = 0; m < 2; ++m)
#pragma unroll
      for (int n = 0; n < 2; ++n)
#pragma unroll
        for (int kk = 0; kk < 2; ++kk)
          acc[m + 2][n + 2] = __builtin_amdgcn_mfma_f32_16x16x32_bf16(af[m][kk], bf23[n][kk], acc[m + 2][n + 2], 0, 0, 0);
    __builtin_amdgcn_s_setprio(0);
    __builtin_amdgcn_s_barrier();

    // ---- P4 ----
    if (t + 2 < NT) stage_tile128(Ag + k2, K, &smA[t & 1][0], tid);
    __builtin_amdgcn_s_barrier();
    __builtin_amdgcn_s_setprio(1);
#pragma unroll
    for (int m = 0; m < 2; ++m)
#pragma unroll
      for (int n = 0; n < 2; ++n)
#pragma unroll
        for (int kk = 0; kk < 2; ++kk)
          acc[m + 2][n] = __builtin_amdgcn_mfma_f32_16x16x32_bf16(af[m][kk], bf01[n][kk], acc[m + 2][n], 0, 0, 0);
    __builtin_amdgcn_s_setprio(0);
    if (t + 2 < NT)
      asm volatile("s_waitcnt vmcnt(6)" ::: "memory");
    else if (t + 2 == NT)
      asm volatile("s_waitcnt vmcnt(0)" ::: "memory");
    __builtin_amdgcn_s_barrier();
  }

#pragma unroll
  for (int m = 0; m < 4; ++m) {
    int row0 = bm + wm * 64 + m * 16 + quad * 4;
#pragma unroll
    for (int n = 0; n < 4; ++n) {
      int col = bn + wn * 64 + n * 16 + l15;
#pragma unroll
      for (int r = 0; r < 4; ++r)
        C[(size_t)(row0 + r) * N + col] = acc[m][n][r];
    }
  }
}

// ---------------- RoPE + scatter (Q pre-scaled by SCALE for attn) ----------------
__global__ void rope_scatter(const float* __restrict__ QKV, const float* __restrict__ cosf,
                             const float* __restrict__ sinf, const int* __restrict__ pos_ids,
                             bf16_t* __restrict__ Qr, bf16_t* __restrict__ Kall,
                             float* __restrict__ outK, float* __restrict__ outV) {
  int m = blockIdx.x;
  int b = m >> 10, s = m & 1023;
  int pos = pos_ids[(size_t)b * Q_ + s];
  const float* row = QKV + (size_t)m * 6144;
  int tid = threadIdx.x;
  for (int p = tid; p < NH_ * 64; p += 256) {
    int h = p >> 6, d = p & 63;
    float x1 = row[h * 128 + d], x2 = row[h * 128 + d + 64];
    float c = cosf[pos * 64 + d], sn = sinf[pos * 64 + d];
    size_t qb = (((size_t)b * NH_ + h) * Q_ + s) * HD_;
    Qr[qb + d] = (bf16_t)((x1 * c - x2 * sn) * SCALE_);
    Qr[qb + d + 64] = (bf16_t)((x2 * c + x1 * sn) * SCALE_);
  }
  for (int p = tid; p < NKV_ * 64; p += 256) {
    int g = p >> 6, d = p & 63;
    float x1 = row[4096 + g * 128 + d], x2 = row[4096 + g * 128 + d + 64];
    float c = cosf[pos * 64 + d], sn = sinf[pos * 64 + d];
    float o1 = x1 * c - x2 * sn, o2 = x2 * c + x1 * sn;
    size_t kbi = (((size_t)b * NKV_ + g) * T_ + PAST_ + s) * HD_;
    Kall[kbi + d] = (bf16_t)o1; Kall[kbi + d + 64] = (bf16_t)o2;
    outK[kbi + d] = o1; outK[kbi + d + 64] = o2;
  }
  for (int e = tid; e < NKV_ * HD_; e += 256) {
    int g = e >> 7, d = e & 127;
    float v = row[5120 + g * 128 + d];
    outV[(((size_t)b * NKV_ + g) * T_ + PAST_ + s) * HD_ + d] = v;
  }
}

// ---------------- flash attention (8 waves x 32 q-rows, QBLK=256) ----------------
__global__ __launch_bounds__(512, 2)
void attn_fwd(const bf16_t* __restrict__ Qr, const bf16_t* __restrict__ Kall,
              const bf16_t* __restrict__ Vt, bf16_t* __restrict__ Ctx) {
  __shared__ bf16_t lK[2][64 * 128];
  __shared__ bf16_t lV[2][128 * 64];
  __shared__ bf16_t lP[8 * 2 * 16 * 64];
  const int tid = threadIdx.x;
  const int wave = tid >> 6, lane = tid & 63;
  const int quad = lane >> 4, l15 = lane & 15;
  const int i = blockIdx.x;
  const int xcd = i & 7;
  const int j = i >> 3;
  const int pairsel = j & 1;
  const int idx = j >> 1;          // 0..15
  const int h_in = idx & 3;
  const int qt = 3 - (idx >> 2);   // heavy first (4 q-tiles of 256 rows)
  const int b = pairsel, kv = xcd;
  const int h = kv * 4 + h_in;
  const int qbase = qt * 256;
  const int wq = qbase + wave * 32;
  const size_t kvbase = ((size_t)b * NKV_ + kv) * T_ * HD_;
  const size_t vtbase = ((size_t)b * NKV_ + kv) * HD_ * T_;

  auto stageKV = [&](int kb, int s) {
#pragma unroll
    for (int t = 0; t < 2; ++t) {
      int c = t * 512 + tid;
      int row = c >> 4, sc = (c & 15) ^ (row & 15);
      int cb = t * 512 + (tid & 448);
      async_cp16(Kall + kvbase + (size_t)(kb + row) * HD_ + sc * 8, lK[s] + (size_t)cb * 8);
    }
#pragma unroll
    for (int t = 0; t < 2; ++t) {
      int c = t * 512 + tid;
      int d = c >> 3, sc = (c & 7) ^ (d & 7);
      int cb = t * 512 + (tid & 448);
      async_cp16(Vt + vtbase + (size_t)d * T_ + kb + sc * 8, lV[s] + (size_t)cb * 8);
    }
  };

  bf16x8 qf[2][4];
#pragma unroll
  for (int g = 0; g < 2; ++g) {
    const bf16_t* qg = Qr + ((((size_t)b * NH_ + h) * Q_) + wq + g * 16 + l15) * HD_ + quad * 8;
#pragma unroll
    for (int kk = 0; kk < 4; ++kk) qf[g][kk] = *(const bf16x8*)(qg + kk * 32);
  }
  bf16x8 ones;
#pragma unroll
  for (int e = 0; e < 8; ++e) ones[e] = (bf16_t)1.0f;

  f32x4 ctx[2][8] = {};
  float Mr[2][4], Lr[2][4];
#pragma unroll
  for (int g = 0; g < 2; ++g)
#pragma unroll
    for (int r = 0; r < 4; ++r) { Mr[g][r] = -3.0e30f; Lr[g][r] = 0.0f; }
  bf16_t* lPw0 = lP + wave * 2048;
  bf16_t* lPw1 = lPw0 + 1024;
  const int nt = (PAST_ + qbase + 256) >> 6;

  stageKV(0, 0);

  for (int ti = 0; ti < nt; ++ti) {
    const int kb = ti << 6;
    const int cur = ti & 1;
    if (ti + 1 < nt) {
      stageKV(kb + 64, cur ^ 1);
      asm volatile("s_waitcnt vmcnt(4)" ::: "memory");
    } else {
      asm volatile("s_waitcnt vmcnt(0)" ::: "memory");
    }
    __builtin_amdgcn_s_barrier();
    asm volatile("" ::: "memory");
    if (kb <= PAST_ + wq + 31) {
      const bf16_t* cK = lK[cur];
      const bf16_t* cV = lV[cur];
      f32x4 sacc[2][4];
#pragma unroll
      for (int g = 0; g < 2; ++g)
#pragma unroll
        for (int nc = 0; nc < 4; ++nc) sacc[g][nc] = (f32x4){0.f, 0.f, 0.f, 0.f};
      __builtin_amdgcn_s_setprio(1);
#pragma unroll
      for (int nc = 0; nc < 4; ++nc) {
        bf16x8 bk[4];
#pragma unroll
        for (int kk = 0; kk < 4; ++kk)
          bk[kk] = *(const bf16x8*)(cK + (nc * 16 + l15) * 128 + (((kk * 4 + quad) ^ l15) << 3));
#pragma unroll
        for (int kk = 0; kk < 4; ++kk)
          sacc[0][nc] = __builtin_amdgcn_mfma_f32_16x16x32_bf16(qf[0][kk], bk[kk], sacc[0][nc], 0, 0, 0);
#pragma unroll
        for (int kk = 0; kk < 4; ++kk)
          sacc[1][nc] = __builtin_amdgcn_mfma_f32_16x16x32_bf16(qf[1][kk], bk[kk], sacc[1][nc], 0, 0, 0);
      }
      __builtin_amdgcn_s_setprio(0);
      bool need = false;
      float tmax[2][4];
#pragma unroll
      for (int g = 0; g < 2; ++g) {
        int wqg = wq + g * 16;
        bool fullvis = (kb + 63 <= PAST_ + wqg);
        if (!fullvis) {
#pragma unroll
          for (int nc = 0; nc < 4; ++nc) {
            int tkey = kb + nc * 16 + l15;
#pragma unroll
            for (int r = 0; r < 4; ++r)
              if (tkey > PAST_ + wqg + quad * 4 + r) sacc[g][nc][r] -= 10000.0f;
          }
        }
#pragma unroll
        for (int r = 0; r < 4; ++r) {
          float tm = fmaxf(fmaxf(sacc[g][0][r], sacc[g][1][r]), fmaxf(sacc[g][2][r], sacc[g][3][r]));
#pragma unroll
          for (int mmk = 1; mmk < 16; mmk <<= 1) tm = fmaxf(tm, __shfl_xor(tm, mmk, 64));
          tmax[g][r] = tm;
          need = need || (tm > Mr[g][r] + 8.0f);
        }
      }
      if (__any(need)) {
#pragma unroll
        for (int g = 0; g < 2; ++g)
#pragma unroll
          for (int r = 0; r < 4; ++r) {
            float nm = fmaxf(Mr[g][r], tmax[g][r]);
            float al = __expf(Mr[g][r] - nm);
            Mr[g][r] = nm;
            Lr[g][r] *= al;
#pragma unroll
            for (int nc2 = 0; nc2 < 8; ++nc2) ctx[g][nc2][r] *= al;
          }
      }
#pragma unroll
      for (int g = 0; g < 2; ++g) {
        bf16_t* lPw = g ? lPw1 : lPw0;
#pragma unroll
        for (int nc = 0; nc < 4; ++nc)
#pragma unroll
          for (int r = 0; r < 4; ++r) {
            float p = __expf(sacc[g][nc][r] - Mr[g][r]);
            int rho = quad * 4 + r;
            int cslot = ((nc * 2 + (l15 >> 3)) ^ (rho & 7));
            lPw[rho * 64 + cslot * 8 + (l15 & 7)] = (bf16_t)p;
          }
      }
      asm volatile("s_waitcnt lgkmcnt(0)" ::: "memory");
      __builtin_amdgcn_sched_barrier(0);
      bf16x8 ap0[2], ap1[2];
#pragma unroll
      for (int kk2 = 0; kk2 < 2; ++kk2) {
        int off = (((kk2 * 4 + quad) ^ (l15 & 7)) << 3);
        ap0[kk2] = *(const bf16x8*)(lPw0 + l15 * 64 + off);
        ap1[kk2] = *(const bf16x8*)(lPw1 + l15 * 64 + off);
      }
      __builtin_amdgcn_s_setprio(1);
      f32x4 ls0 = (f32x4){0.f, 0.f, 0.f, 0.f}, ls1 = (f32x4){0.f, 0.f, 0.f, 0.f};
#pragma unroll
      for (int kk2 = 0; kk2 < 2; ++kk2) {
        ls0 = __builtin_amdgcn_mfma_f32_16x16x32_bf16(ap0[kk2], ones, ls0, 0, 0, 0);
        ls1 = __builtin_amdgcn_mfma_f32_16x16x32_bf16(ap1[kk2], ones, ls1, 0, 0, 0);
      }
#pragma unroll
      for (int nc2 = 0; nc2 < 8; ++nc2)
#pragma unroll
        for (int kk2 = 0; kk2 < 2; ++kk2) {
          bf16x8 bv = *(const bf16x8*)(cV + (nc2 * 16 + l15) * 64 + (((kk2 * 4 + quad) ^ (l15 & 7)) << 3));
          ctx[0][nc2] = __builtin_amdgcn_mfma_f32_16x16x32_bf16(ap0[kk2], bv, ctx[0][nc2], 0, 0, 0);
          ctx[1][nc2] = __builtin_amdgcn_mfma_f32_16x16x32_bf16(ap1[kk2], bv, ctx[1][nc2], 0, 0, 0);
        }
      __builtin_amdgcn_s_setprio(0);
#pragma unroll
      for (int r = 0; r < 4; ++r) { Lr[0][r] += ls0[r]; Lr[1][r] += ls1[r]; }
    }
    __builtin_amdgcn_sched_barrier(0);
    __builtin_amdgcn_s_barrier();
  }
#pragma unroll
  for (int g = 0; g < 2; ++g) {
    float inv[4];
#pragma unroll
    for (int r = 0; r < 4; ++r) inv[r] = 1.0f / Lr[g][r];
#pragma unroll
    for (int nc2 = 0; nc2 < 8; ++nc2)
#pragma unroll
      for (int r = 0; r < 4; ++r) {
        size_t row = (size_t)b * Q_ + wq + g * 16 + quad * 4 + r;
        Ctx[row * (NH_ * HD_) + h * HD_ + nc2 * 16 + l15] = (bf16_t)(ctx[g][nc2][r] * inv[r]);
      }
  }
}

extern "C" void kernel_launch(void* const* d_in, const int* in_sizes, int n_in,
                              void* d_out, int out_size, void* d_ws, size_t ws_size,
                              hipStream_t stream) {
  const float* hidden = (const float*)d_in[0];
  const int* pos = (const int*)d_in[2];
  const float* cosf = (const float*)d_in[3];
  const float* sinf = (const float*)d_in[4];
  const float* past_k = (const float*)d_in[5];
  const float* past_v = (const float*)d_in[6];
  const float* q_w = (const float*)d_in[7];
  const float* k_w = (const float*)d_in[8];
  const float* v_w = (const float*)d_in[9];
  const float* o_w = (const float*)d_in[10];

  float* attn_out = (float*)d_out;
  float* outK = attn_out + (size_t)B_ * Q_ * HID_;
  float* outV = outK + (size_t)B_ * NKV_ * T_ * HD_;

  if (ws_size < 150994944) return;
  char* ws = (char*)d_ws;
  bf16_t* Wqkv = (bf16_t*)(ws);              // 48 MiB
  bf16_t* Xb   = (bf16_t*)(ws + 50331648);   // 16 MiB
  float*  QKV  = (float*)(ws + 67108864);    // 48 MiB
  bf16_t* Qr   = (bf16_t*)(ws + 117440512);  // 16 MiB
  bf16_t* Kall = (bf16_t*)(ws + 134217728);  // 8 MiB
  bf16_t* Vt   = (bf16_t*)(ws + 142606336);  // 8 MiB (d-major transposed V)
  bf16_t* Wo   = (bf16_t*)(ws + 67108864);   // alias QKV (converted after build_vt)
  bf16_t* Ctx  = (bf16_t*)(ws + 50331648);   // alias Xb (written after gemm1)

  cvt_f32_bf16<<<4096, 256, 0, stream>>>(hidden, Xb, 8388608);
  cvt_f32_bf16<<<8192, 256, 0, stream>>>(q_w, Wqkv, 16777216);
  cvt_f32_bf16<<<2048, 256, 0, stream>>>(k_w, Wqkv + 16777216, 4194304);
  cvt_f32_bf16<<<2048, 256, 0, stream>>>(v_w, Wqkv + 20971520, 4194304);
  copy_past<<<dim3(16, 8, 2), 256, 0, stream>>>(past_k, past_v, outK, outV, Kall, Vt);
  gemm192<<<dim3(32, 8), 512, 0, stream>>>(Xb, Wqkv, QKV, 2048, 6144, 4096);
  rope_scatter<<<2048, 256, 0, stream>>>(QKV, cosf, sinf, pos, Qr, Kall, outK, outV);
  build_vt<<<dim3(16, 8, 2), 256, 0, stream>>>(QKV, Vt);
  cvt_f32_bf16<<<8192, 256, 0, stream>>>(o_w, Wo, 16777216);  // after QKV consumed
  attn_fwd<<<256, 512, 0, stream>>>(Qr, Kall, Vt, Ctx);
  gemm128<<<dim3(16, 16), 512, 0, stream>>>(Ctx, Wo, attn_out, 2048, 4096, 4096);
}